// Round 6
// baseline (806.030 us; speedup 1.0000x reference)
//
#include <hip/hip_runtime.h>
#include <math.h>

#define NA 512
#define NN (NA*NA)
#define COULOMB 14.399645478425668f
#define SQRT_PI 1.7724538509055160273f

// tail-fusion region: last 192 rows/cols handled by k_tail in LDS
#define TB 320
#define TS 192
#define TSTR 193

typedef float v2f __attribute__((ext_vector_type(2)));

__device__ __forceinline__ float rl(float x, int lane) {
    return __int_as_float(__builtin_amdgcn_readlane(__float_as_int(x), lane));
}

__device__ __forceinline__ float pair_val(float dx, float dy, float dz,
                                          float s2i, float s2k) {
    float d2 = dx*dx + dy*dy + dz*dz;
    float rinv = rsqrtf(d2);
    return COULOMB * erff(d2 * rinv * rsqrtf(2.f * (s2i + s2k))) * rinv;
}

// ---------------------------------------------------------------- K1: per-atom
// Also initializes the two RHS vectors: r1 = chi, r2 = 1.
__global__ void k_pre(const float* __restrict__ feats, const float* __restrict__ w,
                      const int* __restrict__ type, const float* __restrict__ hard,
                      const float* __restrict__ sigma,
                      float* __restrict__ chi, float* __restrict__ diag,
                      float* __restrict__ sigA,
                      float* __restrict__ r1, float* __restrict__ r2, int N) {
    __shared__ float wl[64];
    int tid = threadIdx.x;
    if (tid < 64) wl[tid] = w[tid];
    __syncthreads();
    int i = blockIdx.x * 256 + tid;
    if (i >= N) return;
    const float4* fp = (const float4*)(feats + (size_t)i * 64);
    float acc = 0.f;
#pragma unroll
    for (int q = 0; q < 16; q++) {
        float4 v = fp[q];
        acc += v.x * wl[4*q] + v.y * wl[4*q+1] + v.z * wl[4*q+2] + v.w * wl[4*q+3];
    }
    chi[i] = acc;
    r1[i] = acc;
    r2[i] = 1.0f;
    int t = type[i];
    float s = sigma[t];
    float h = hard[t];
    sigA[i] = s;
    diag[i] = h * h + COULOMB / (SQRT_PI * s);
}

// ------------------------------------------- K2: diag factor + split panel trsm (j<=4)
// Forward substitution for BOTH RHS fused here (round-11 proven).
__global__ void __launch_bounds__(256, 1) k_panel(const float* __restrict__ pos,
                                                  const float* __restrict__ sigA,
                                                  const float* __restrict__ diagA,
                                                  float* __restrict__ C,
                                                  float* __restrict__ r1,
                                                  float* __restrict__ r2, const int j) {
    const int q = blockIdx.x;
    const int b = blockIdx.y;
    float* __restrict__ Cb = C + (size_t)b * NN;
    const int jb = j * 64;
    const int m = NA - jb - 64;
    const int tid = threadIdx.x;
    __shared__ float D[64 * 65];
    __shared__ float DT[64 * 64];
    __shared__ float invd[64];
    __shared__ float y1s[64], y2s[64];
    __shared__ float px[NA], py[NA], pz[NA], s2s[NA];

    if (j == 0) {
#pragma unroll
        for (int e = 0; e < 2; e++) {
            int i = e * 256 + tid;
            px[i] = pos[((size_t)b * NA + i) * 3 + 0];
            py[i] = pos[((size_t)b * NA + i) * 3 + 1];
            pz[i] = pos[((size_t)b * NA + i) * 3 + 2];
            float s = sigA[b * NA + i];
            s2s[i] = s * s;
        }
        __syncthreads();
    }

#pragma unroll
    for (int e = 0; e < 16; e++) {
        int f = e * 256 + tid;
        int rr = f >> 6, cc = f & 63;
        float v;
        if (j == 0) {
            if (rr == cc) v = diagA[b * NA + rr];
            else v = pair_val(px[rr]-px[cc], py[rr]-py[cc], pz[rr]-pz[cc], s2s[rr], s2s[cc]);
        } else {
            v = Cb[(size_t)(jb + rr) * NA + jb + cc];
        }
        D[rr * 65 + cc] = v;
    }

    const int h = m >> 1;
    const int r0 = q ? h : 0;
    const int nr = q ? (m - h) : h;
    const int r = tid - 32;
    const bool hasrow = (r >= 0 && r < nr);
    const int grow = jb + 64 + r0 + r;
    float rv[64];
    if (hasrow) {
        if (j == 0) {
#pragma unroll
            for (int k = 0; k < 64; k++)
                rv[k] = pair_val(px[grow]-px[k], py[grow]-py[k], pz[grow]-pz[k],
                                 s2s[grow], s2s[k]);
        } else {
            const float4* rp = (const float4*)(Cb + (size_t)grow * NA + jb);
#pragma unroll
            for (int qq = 0; qq < 16; qq++) {
                float4 v = rp[qq];
                rv[4*qq] = v.x; rv[4*qq+1] = v.y; rv[4*qq+2] = v.z; rv[4*qq+3] = v.w;
            }
        }
    }
    __syncthreads();

    if (tid < 64) {
        const int t = tid;
        float cl[64];
#pragma unroll
        for (int i = 0; i < 64; i++) cl[i] = (i >= t) ? D[i * 65 + t] : D[t * 65 + i];
#pragma unroll
        for (int k = 0; k < 64; k++) {
            float pivot = rl(cl[k], k);
            float invp = 1.0f / pivot;
            float factor = (t > k) ? (cl[k] * invp) : 0.0f;
#pragma unroll
            for (int i = k + 1; i < 64; i++) {
                float bc = rl(cl[i], k);
                cl[i] -= bc * factor;
            }
        }
        float rs = 1.0f / sqrtf(cl[t]);
        invd[t] = rs;
#pragma unroll
        for (int i = 0; i < 64; i++)
            if (i >= t) D[i * 65 + t] = cl[i] * rs;

        // ---- fused forward substitution: solve L_jj y = r_j for both RHS.
        float v1 = r1[(size_t)b * NA + jb + t];
        float v2 = r2[(size_t)b * NA + jb + t];
#pragma unroll
        for (int k = 0; k < 64; k++) {
            float rsk = rl(rs, k);
            float y1k = rl(v1, k) * rsk;
            float y2k = rl(v2, k) * rsk;
            if (t == k) {
                y1s[t] = y1k; y2s[t] = y2k;
                if (q == 0) {
                    r1[(size_t)b * NA + jb + t] = y1k;
                    r2[(size_t)b * NA + jb + t] = y2k;
                }
            }
            float lv = (t > k) ? D[t * 65 + k] : 0.f;
            v1 -= lv * y1k;
            v2 -= lv * y2k;
        }
    }
    __syncthreads();

#pragma unroll
    for (int e = 0; e < 16; e++) {
        int f = e * 256 + tid;
        int row = f >> 6, cc = f & 63;
        float v = D[row * 65 + cc];
        DT[row * 64 + cc] = (cc < row) ? v : 0.f;
        if (q == 0 && cc <= row) Cb[(size_t)(jb + row) * NA + jb + cc] = v;
    }
    __syncthreads();

    if (hasrow) {
#pragma unroll
        for (int k = 0; k < 64; k++) {
            float acc = rv[k];
            const float4* Lr = (const float4*)(DT + k * 64);
            const int k4 = k >> 2;
#pragma unroll
            for (int t4 = 0; t4 < k4; t4++) {
                float4 Lv = Lr[t4];
                acc -= Lv.x * rv[4*t4] + Lv.y * rv[4*t4+1] + Lv.z * rv[4*t4+2] + Lv.w * rv[4*t4+3];
            }
#pragma unroll
            for (int tt = k4 * 4; tt < k; tt++) acc -= DT[k * 64 + tt] * rv[tt];
            rv[k] = acc * invd[k];
        }
        float4* rp = (float4*)(Cb + (size_t)grow * NA + jb);
#pragma unroll
        for (int qq = 0; qq < 16; qq++)
            rp[qq] = make_float4(rv[4*qq], rv[4*qq+1], rv[4*qq+2], rv[4*qq+3]);

        // ---- fused forward update: r[grow] -= L_row . y_j (both RHS).
        float a1 = 0.f, a2 = 0.f;
#pragma unroll
        for (int k = 0; k < 64; k++) {
            a1 = fmaf(rv[k], y1s[k], a1);
            a2 = fmaf(rv[k], y2s[k], a2);
        }
        r1[(size_t)b * NA + grow] -= a1;
        r2[(size_t)b * NA + grow] -= a2;
    }
}

// ------------------------------------------- K3: trailing update (j<=4) — round-13 proven
template<bool GEN>
__global__ void __launch_bounds__(256, 2) k_trail(float* __restrict__ C,
                                                  const float* __restrict__ pos,
                                                  const float* __restrict__ sigA,
                                                  const float* __restrict__ diagA,
                                                  const int j) {
    const int b = blockIdx.y;
    float* __restrict__ Cb = C + (size_t)b * NN;
    const int jb = j * 64;
    const int m = NA - jb - 64;
    int t = blockIdx.x;
    int RI = 0;
    while (t >= RI + 1) { t -= RI + 1; RI++; }
    const int RJ = t;
    const int RB = RI * 128, CB = RJ * 128;
    const int vr = min(128, m - RB);
    const int vc = min(128, m - CB);
    const int tid = threadIdx.x;
    const int rg = tid >> 4, cg = tid & 15;

    __shared__ float As[128 * 66];
    __shared__ float Bs[128 * 66];

    v2f ac2[8][8];

    if (GEN) {
        __shared__ float pAx[128], pAy[128], pAz[128], sA[128], dA[128];
        __shared__ float pBx[128], pBy[128], pBz[128], sB[128];
        if (tid < 128) {
            if (RB + tid < m) {
                int ga = b * NA + jb + 64 + RB + tid;
                pAx[tid] = pos[(size_t)ga * 3 + 0];
                pAy[tid] = pos[(size_t)ga * 3 + 1];
                pAz[tid] = pos[(size_t)ga * 3 + 2];
                float s = sigA[ga]; sA[tid] = s * s;
                dA[tid] = diagA[ga];
            }
        } else {
            int u = tid - 128;
            if (CB + u < m) {
                int gb = b * NA + jb + 64 + CB + u;
                pBx[u] = pos[(size_t)gb * 3 + 0];
                pBy[u] = pos[(size_t)gb * 3 + 1];
                pBz[u] = pos[(size_t)gb * 3 + 2];
                float s = sigA[gb]; sB[u] = s * s;
            }
        }
        __syncthreads();
#pragma unroll
        for (int rr = 0; rr < 8; rr++) {
            int row = rg * 8 + rr;
#pragma unroll
            for (int cc = 0; cc < 8; cc++) {
                int col = cg + 16 * cc;
                float iv;
                if (RB + row == CB + col)
                    iv = dA[row];
                else
                    iv = pair_val(pAx[row]-pBx[col], pAy[row]-pBy[col],
                                  pAz[row]-pBz[col], sA[row], sB[col]);
                ac2[rr][cc].x = iv;
                ac2[rr][cc].y = 0.f;
            }
        }
        __syncthreads();
    } else {
        const int GRB = jb + 64 + RB, GCB = jb + 64 + CB;
#pragma unroll
        for (int rr = 0; rr < 8; rr++) {
            int row = rg * 8 + rr;
#pragma unroll
            for (int cc = 0; cc < 8; cc++) {
                int col = cg + 16 * cc;
                ac2[rr][cc].x = (row < vr && col < vc)
                    ? Cb[(size_t)(GRB + row) * NA + GCB + col] : 0.f;
                ac2[rr][cc].y = 0.f;
            }
        }
    }

    const float* Pan = Cb + (size_t)(jb + 64) * NA + jb;
#pragma unroll
    for (int e = 0; e < 8; e++) {
        int f = e * 256 + tid;
        int row = f >> 4, s = f & 15;
        float4 v = make_float4(0.f, 0.f, 0.f, 0.f);
        if (row < vr) v = *(const float4*)(Pan + (size_t)(RB + row) * NA + s * 4);
        As[row * 66 + s * 4 + 0] = v.x;
        As[row * 66 + s * 4 + 1] = v.y;
        As[row * 66 + s * 4 + 2] = v.z;
        As[row * 66 + s * 4 + 3] = v.w;
        float4 u = make_float4(0.f, 0.f, 0.f, 0.f);
        if (row < vc) u = *(const float4*)(Pan + (size_t)(CB + row) * NA + s * 4);
        Bs[row * 66 + s * 4 + 0] = u.x;
        Bs[row * 66 + s * 4 + 1] = u.y;
        Bs[row * 66 + s * 4 + 2] = u.z;
        Bs[row * 66 + s * 4 + 3] = u.w;
    }
    __syncthreads();

#pragma unroll 2
    for (int k = 0; k < 64; k += 2) {
        v2f ai2[8], bj2[8];
#pragma unroll
        for (int rr = 0; rr < 8; rr++)
            ai2[rr] = *(const v2f*)&As[(rg * 8 + rr) * 66 + k];
#pragma unroll
        for (int cc = 0; cc < 8; cc++)
            bj2[cc] = *(const v2f*)&Bs[(cg + 16 * cc) * 66 + k];
#pragma unroll
        for (int rr = 0; rr < 8; rr++)
#pragma unroll
            for (int cc = 0; cc < 8; cc++) {
                ac2[rr][cc].x = fmaf(-ai2[rr].x, bj2[cc].x, ac2[rr][cc].x);
                ac2[rr][cc].y = fmaf(-ai2[rr].y, bj2[cc].y, ac2[rr][cc].y);
            }
    }

    const int GRB = jb + 64 + RB, GCB = jb + 64 + CB;
#pragma unroll
    for (int rr = 0; rr < 8; rr++) {
        int row = rg * 8 + rr;
        if (row < vr) {
#pragma unroll
            for (int cc = 0; cc < 8; cc++) {
                int col = cg + 16 * cc;
                if (col < vc)
                    Cb[(size_t)(GRB + row) * NA + GCB + col] = ac2[rr][cc].x + ac2[rr][cc].y;
            }
        }
    }
}

// ---- trsm-as-GEMM helper for k_tail: thread owns row `row_l`, computes
// X[row_l][i] = sum_{k<=i} A[row_l][k] * M[i][k] for i = PART + S*q, q in [0,NQ).
// M[i][k] (k<i) lives at T[row k][col i] (strict upper of diag block);
// M[i][i] = invd[i]. All M reads are wave-uniform broadcasts (PART uniform/wave).
template<int S, int NQ, int PART>
__device__ __forceinline__ void trsm_rows(float* __restrict__ T,
                                          const float* __restrict__ invd,
                                          const int pb, const int row_l) {
    float rv[64];
    const float* Ar = &T[row_l * TSTR + pb];
#pragma unroll
    for (int k4 = 0; k4 < 16; k4++) {
        float4 v = *(const float4*)(Ar + 4 * k4);
        rv[4*k4+0] = v.x; rv[4*k4+1] = v.y; rv[4*k4+2] = v.z; rv[4*k4+3] = v.w;
    }
    float x[NQ];
#pragma unroll
    for (int q = 0; q < NQ; q++) x[q] = 0.f;
#pragma unroll
    for (int k = 0; k < 64; k++) {
        const float a = rv[k];
        const float* Mrow = &T[(pb + k) * TSTR + pb];
#pragma unroll
        for (int q = 0; q < NQ; q++) {
            const int i = PART + S * q;
            if (i > k)       x[q] = fmaf(a, Mrow[i], x[q]);
            else if (i == k) x[q] = fmaf(a, invd[k], x[q]);
        }
    }
#pragma unroll
    for (int q = 0; q < NQ; q++)
        T[row_l * TSTR + pb + PART + S * q] = x[q];
}

// ------------------------------------------- K3b: fused tail (j=5,6,7) — one block/molecule
// Round-14: serial per-row trsm replaced by explicit diag-block inverse M = L^-1
// (computed in-wave right after the factor, ~2080 readlane+FMA, no LDS) + a fully
// parallel triangular GEMM X = A * M^T across all 256 threads. M is stored in the
// strict UPPER triangle of the diag block (dead space — k_back and store-back read
// lower+diag only). r1/r2 forward-update is a separate parallel dot pass.
__global__ void __launch_bounds__(256, 1) k_tail(float* __restrict__ C,
                                                 float* __restrict__ r1,
                                                 float* __restrict__ r2) {
    const int b = blockIdx.x;
    float* __restrict__ Cb = C + (size_t)b * NN;
    const int tid = threadIdx.x;
    __shared__ float T[TS * TSTR];
    __shared__ float invd[64], y1s[64], y2s[64];

    for (int f = tid; f < TS * TS; f += 256) {
        int row = f / TS, c = f - row * TS;
        T[row * TSTR + c] = Cb[(size_t)(TB + row) * NA + TB + c];
    }
    __syncthreads();

#pragma unroll 1
    for (int p = 0; p < 3; p++) {
        const int pb = p * 64;
        const int msub = TS - pb - 64;

        if (tid < 64) {
            const int t = tid;
            float cl[64];
#pragma unroll
            for (int i = 0; i < 64; i++)
                cl[i] = (i >= t) ? T[(pb + i) * TSTR + pb + t]
                                 : T[(pb + t) * TSTR + pb + i];
#pragma unroll
            for (int k = 0; k < 64; k++) {
                float pivot = rl(cl[k], k);
                float invp = 1.0f / pivot;
                float factor = (t > k) ? (cl[k] * invp) : 0.0f;
#pragma unroll
                for (int i = k + 1; i < 64; i++) {
                    float bc = rl(cl[i], k);
                    cl[i] -= bc * factor;
                }
            }
            float rs = 1.0f / sqrtf(cl[t]);
            invd[t] = rs;
            float ls[64];
#pragma unroll
            for (int i = 0; i < 64; i++) ls[i] = cl[i] * rs;   // L[i][t], valid i>=t
#pragma unroll
            for (int i = 0; i < 64; i++)
                if (i >= t) T[(pb + i) * TSTR + pb + t] = ls[i];   // L lower+diag

            if (p < 2) {
                // ---- invert: lane t builds column t of M = L^-1 (m[i] = M[i][t])
                float m[64];
#pragma unroll
                for (int i = 0; i < 64; i++) m[i] = (i == t) ? rs : 0.f;
#pragma unroll
                for (int k = 1; k < 64; k++) {
                    float acc = 0.f;
#pragma unroll
                    for (int jj = 0; jj < k; jj++)
                        acc += rl(ls[k], jj) * m[jj];          // L[k][jj] broadcast
                    float mk = -rl(rs, k) * acc;
                    if (t < k) m[k] = mk;
                }
                // store M^T into strict upper: T[row t][col k] = M[k][t], k>t
#pragma unroll
                for (int k = 0; k < 64; k++)
                    if (k > t) T[(pb + t) * TSTR + pb + k] = m[k];
            }

            // ---- fused forward substitution, both RHS (uses L lower in T)
            float v1 = r1[(size_t)b * NA + TB + pb + t];
            float v2 = r2[(size_t)b * NA + TB + pb + t];
#pragma unroll
            for (int k = 0; k < 64; k++) {
                float rsk = rl(rs, k);
                float y1k = rl(v1, k) * rsk;
                float y2k = rl(v2, k) * rsk;
                if (t == k) {
                    y1s[t] = y1k; y2s[t] = y2k;
                    r1[(size_t)b * NA + TB + pb + t] = y1k;
                    r2[(size_t)b * NA + TB + pb + t] = y2k;
                }
                float lv = (t > k) ? T[(pb + t) * TSTR + pb + k] : 0.f;
                v1 -= lv * y1k;
                v2 -= lv * y2k;
            }
        }
        __syncthreads();

        if (msub > 0) {
            // ---- trsm as GEMM: all 256 threads, interleaved column split
            if (p == 0) {
                const int row_l = pb + 64 + (tid & 127);
                if ((tid >> 7) == 0) trsm_rows<2, 32, 0>(T, invd, pb, row_l);
                else                 trsm_rows<2, 32, 1>(T, invd, pb, row_l);
            } else {
                const int row_l = pb + 64 + (tid & 63);
                const int part = tid >> 6;
                if      (part == 0) trsm_rows<4, 16, 0>(T, invd, pb, row_l);
                else if (part == 1) trsm_rows<4, 16, 1>(T, invd, pb, row_l);
                else if (part == 2) trsm_rows<4, 16, 2>(T, invd, pb, row_l);
                else                trsm_rows<4, 16, 3>(T, invd, pb, row_l);
            }
            __syncthreads();

            // ---- forward update r -= X . y (parallel dot per row)
            if (tid < msub) {
                const int row_l = pb + 64 + tid;
                float a1 = 0.f, a2 = 0.f;
#pragma unroll
                for (int k = 0; k < 64; k++) {
                    float xv = T[row_l * TSTR + pb + k];
                    a1 = fmaf(xv, y1s[k], a1);
                    a2 = fmaf(xv, y2s[k], a2);
                }
                r1[(size_t)b * NA + TB + row_l] -= a1;
                r2[(size_t)b * NA + TB + row_l] -= a2;
            }

            const int rbase = pb + 64;
            if (p == 0) {
                // 128x128 trailing, 8x8 per thread
                const int rg = tid >> 4, cg = tid & 15;
                float acc[8][8];
#pragma unroll
                for (int rr = 0; rr < 8; rr++)
#pragma unroll
                    for (int cc = 0; cc < 8; cc++)
                        acc[rr][cc] = T[(rbase + rg * 8 + rr) * TSTR + rbase + cg * 8 + cc];
#pragma unroll 4
                for (int k = 0; k < 64; k++) {
                    float ai[8], bj[8];
#pragma unroll
                    for (int rr = 0; rr < 8; rr++)
                        ai[rr] = T[(rbase + rg * 8 + rr) * TSTR + pb + k];
#pragma unroll
                    for (int cc = 0; cc < 8; cc++)
                        bj[cc] = T[(rbase + cg * 8 + cc) * TSTR + pb + k];
#pragma unroll
                    for (int rr = 0; rr < 8; rr++)
#pragma unroll
                        for (int cc = 0; cc < 8; cc++)
                            acc[rr][cc] = fmaf(-ai[rr], bj[cc], acc[rr][cc]);
                }
#pragma unroll
                for (int rr = 0; rr < 8; rr++)
#pragma unroll
                    for (int cc = 0; cc < 8; cc++)
                        T[(rbase + rg * 8 + rr) * TSTR + rbase + cg * 8 + cc] = acc[rr][cc];
            } else {
                // 64x64 trailing, 4x4 per thread
                const int rg = tid >> 4, cg = tid & 15;
                float acc[4][4];
#pragma unroll
                for (int rr = 0; rr < 4; rr++)
#pragma unroll
                    for (int cc = 0; cc < 4; cc++)
                        acc[rr][cc] = T[(rbase + rg * 4 + rr) * TSTR + rbase + cg * 4 + cc];
#pragma unroll 4
                for (int k = 0; k < 64; k++) {
                    float ai[4], bj[4];
#pragma unroll
                    for (int rr = 0; rr < 4; rr++)
                        ai[rr] = T[(rbase + rg * 4 + rr) * TSTR + pb + k];
#pragma unroll
                    for (int cc = 0; cc < 4; cc++)
                        bj[cc] = T[(rbase + cg * 4 + cc) * TSTR + pb + k];
#pragma unroll
                    for (int rr = 0; rr < 4; rr++)
#pragma unroll
                        for (int cc = 0; cc < 4; cc++)
                            acc[rr][cc] = fmaf(-ai[rr], bj[cc], acc[rr][cc]);
                }
#pragma unroll
                for (int rr = 0; rr < 4; rr++)
#pragma unroll
                    for (int cc = 0; cc < 4; cc++)
                        T[(rbase + rg * 4 + rr) * TSTR + rbase + cg * 4 + cc] = acc[rr][cc];
            }
        }
        __syncthreads();
    }

    for (int f = tid; f < TS * TS; f += 256) {
        int row = f / TS, c = f - row * TS;
        Cb[(size_t)(TB + row) * NA + TB + c] = T[row * TSTR + c];
    }
}

// ------------------------------------------- K4: backward-only solve (grid = B x 2)
__global__ void __launch_bounds__(512, 1) k_back(const float* __restrict__ C,
                                                 float* __restrict__ r1g,
                                                 float* __restrict__ r2g) {
    const int b = blockIdx.x;
    const int rhs = blockIdx.y;
    const float* Cb = C + (size_t)b * NN;
    const int tid = threadIdx.x;
    __shared__ float D[64 * 65];
    __shared__ float r[NA];
    __shared__ float pb[4][NA];

    float* rg = rhs ? r2g : r1g;
    r[tid] = rg[(size_t)b * NA + tid];

    const int ii = tid & 127;
    const int gg = tid >> 7;
    for (int j = 7; j >= 0; j--) {
        const int jb = j * 64;
        __syncthreads();
#pragma unroll
        for (int e = 0; e < 8; e++) {
            int f = e * 512 + tid;
            int row = f >> 6, cc = f & 63;
            D[row * 65 + cc] = Cb[(size_t)(jb + row) * NA + jb + cc];
        }
        __syncthreads();
        if (tid < 64) {
            float val = r[jb + tid];
            float idg = 1.0f / D[tid * 65 + tid];
#pragma unroll
            for (int k = 63; k >= 0; k--) {
                float xk = rl(val, k) * rl(idg, k);
                if (tid == k) r[jb + k] = xk;
                float lv = (tid < k) ? D[k * 65 + tid] : 0.f;
                val -= lv * xk;
            }
        }
        __syncthreads();
        if (jb > 0) {
            const int nf4 = jb >> 2;
            float4 s1 = make_float4(0.f, 0.f, 0.f, 0.f);
            if (ii < nf4) {
#pragma unroll
                for (int gq = 0; gq < 16; gq++) {
                    int g = jb + gg * 16 + gq;
                    float x1 = r[g];
                    float4 Lv = *(const float4*)(Cb + (size_t)g * NA + ii * 4);
                    s1.x += Lv.x * x1; s1.y += Lv.y * x1; s1.z += Lv.z * x1; s1.w += Lv.w * x1;
                }
            }
            *(float4*)(&pb[gg][ii * 4]) = s1;
            __syncthreads();
            if (tid < jb)
                r[tid] -= pb[0][tid] + pb[1][tid] + pb[2][tid] + pb[3][tid];
        }
    }
    __syncthreads();

    rg[(size_t)b * NA + tid] = r[tid];
}

// ------------------------------------------- K5: mu, q, energy from x1, x2
__global__ void __launch_bounds__(512, 1) k_final(const float* __restrict__ x1,
                                                  const float* __restrict__ x2,
                                                  const float* __restrict__ chiA,
                                                  const float* __restrict__ Qtot,
                                                  float* __restrict__ out, int B) {
    const int b = blockIdx.x;
    const int tid = threadIdx.x;
    __shared__ float red[16];
    __shared__ float muS;

    float v1 = x1[(size_t)b * NA + tid];
    float v2 = x2[(size_t)b * NA + tid];

    float s1p = v1, s2p = v2;
#pragma unroll
    for (int off = 1; off < 64; off <<= 1) {
        s1p += __shfl_xor(s1p, off);
        s2p += __shfl_xor(s2p, off);
    }
    if ((tid & 63) == 0) { red[tid >> 6] = s1p; red[8 + (tid >> 6)] = s2p; }
    __syncthreads();
    if (tid == 0) {
        float s1 = 0.f, s2 = 0.f;
#pragma unroll
        for (int wv = 0; wv < 8; wv++) { s1 += red[wv]; s2 += red[8 + wv]; }
        muS = -(Qtot[b] + s1) / s2;
    }
    __syncthreads();
    float mu = muS;
    float qv = -v1 - mu * v2;
    out[B + (size_t)b * NA + tid] = qv;

    float eacc = chiA[b * NA + tid] * qv;
#pragma unroll
    for (int off = 1; off < 64; off <<= 1) eacc += __shfl_xor(eacc, off);
    __syncthreads();
    if ((tid & 63) == 0) red[tid >> 6] = eacc;
    __syncthreads();
    if (tid == 0) {
        float e = 0.f;
#pragma unroll
        for (int wv = 0; wv < 8; wv++) e += red[wv];
        out[b] = 0.5f * e - 0.5f * mu * Qtot[b];
    }
}

// ---------------------------------------------------------------- host launch
extern "C" void kernel_launch(void* const* d_in, const int* in_sizes, int n_in,
                              void* d_out, int out_size, void* d_ws, size_t ws_size,
                              hipStream_t stream) {
    const int B = in_sizes[3];          // 128 molecules
    const int N = in_sizes[2];          // 65536 atoms
    const float* feats = (const float*)d_in[0];
    const float* pos   = (const float*)d_in[1];
    const int*   type  = (const int*)d_in[2];
    const float* Qt    = (const float*)d_in[3];
    const float* w     = (const float*)d_in[4];
    const float* hard  = (const float*)d_in[5];
    const float* sig   = (const float*)d_in[6];
    float* out = (float*)d_out;
    float* ws  = (float*)d_ws;

    float* C    = ws;                       // B * 512 * 512
    float* chi  = ws + (size_t)B * NN;      // N
    float* diag = chi + N;                  // N
    float* sigA = diag + N;                 // N
    float* r1   = sigA + N;                 // N (rhs1: chi -> y -> x1)
    float* r2   = r1 + N;                   // N (rhs2: 1   -> y -> x2)

    k_pre<<<(N + 255) / 256, 256, 0, stream>>>(feats, w, type, hard, sig,
                                               chi, diag, sigA, r1, r2, N);

    static const int tilesJ[5] = {10, 6, 6, 3, 3};
    for (int j = 0; j < 5; j++) {
        k_panel<<<dim3(2, B), 256, 0, stream>>>(pos, sigA, diag, C, r1, r2, j);
        if (j == 0)
            k_trail<true><<<dim3(tilesJ[j], B), 256, 0, stream>>>(C, pos, sigA, diag, j);
        else
            k_trail<false><<<dim3(tilesJ[j], B), 256, 0, stream>>>(C, pos, sigA, diag, j);
    }
    k_tail<<<B, 256, 0, stream>>>(C, r1, r2);
    k_back<<<dim3(B, 2), 512, 0, stream>>>(C, r1, r2);
    k_final<<<B, 512, 0, stream>>>(r1, r2, chi, Qt, out, B);
}

// Round 8
// 730.098 us; speedup vs baseline: 1.1040x; 1.1040x over previous
//
#include <hip/hip_runtime.h>
#include <math.h>

#define NA 512
#define NN (NA*NA)
#define COULOMB 14.399645478425668f
#define SQRT_PI 1.7724538509055160273f

// tail-fusion region: last 192 rows/cols handled by k_tail in LDS
#define TB 320
#define TS 192
#define TSTR 193

typedef float v2f __attribute__((ext_vector_type(2)));

__device__ __forceinline__ float rl(float x, int lane) {
    return __int_as_float(__builtin_amdgcn_readlane(__float_as_int(x), lane));
}

__device__ __forceinline__ float pair_val(float dx, float dy, float dz,
                                          float s2i, float s2k) {
    float d2 = dx*dx + dy*dy + dz*dz;
    float rinv = rsqrtf(d2);
    return COULOMB * erff(d2 * rinv * rsqrtf(2.f * (s2i + s2k))) * rinv;
}

// ---------------------------------------------------------------- K1: per-atom
// Also initializes the two RHS vectors: r1 = chi, r2 = 1.
__global__ void k_pre(const float* __restrict__ feats, const float* __restrict__ w,
                      const int* __restrict__ type, const float* __restrict__ hard,
                      const float* __restrict__ sigma,
                      float* __restrict__ chi, float* __restrict__ diag,
                      float* __restrict__ sigA,
                      float* __restrict__ r1, float* __restrict__ r2, int N) {
    __shared__ float wl[64];
    int tid = threadIdx.x;
    if (tid < 64) wl[tid] = w[tid];
    __syncthreads();
    int i = blockIdx.x * 256 + tid;
    if (i >= N) return;
    const float4* fp = (const float4*)(feats + (size_t)i * 64);
    float acc = 0.f;
#pragma unroll
    for (int q = 0; q < 16; q++) {
        float4 v = fp[q];
        acc += v.x * wl[4*q] + v.y * wl[4*q+1] + v.z * wl[4*q+2] + v.w * wl[4*q+3];
    }
    chi[i] = acc;
    r1[i] = acc;
    r2[i] = 1.0f;
    int t = type[i];
    float s = sigma[t];
    float h = hard[t];
    sigA[i] = s;
    diag[i] = h * h + COULOMB / (SQRT_PI * s);
}

// ------------------------------------------- K2: diag factor + split panel trsm (j<=4)
// Forward substitution for BOTH RHS fused here (round-11 proven).
__global__ void __launch_bounds__(256, 1) k_panel(const float* __restrict__ pos,
                                                  const float* __restrict__ sigA,
                                                  const float* __restrict__ diagA,
                                                  float* __restrict__ C,
                                                  float* __restrict__ r1,
                                                  float* __restrict__ r2, const int j) {
    const int q = blockIdx.x;
    const int b = blockIdx.y;
    float* __restrict__ Cb = C + (size_t)b * NN;
    const int jb = j * 64;
    const int m = NA - jb - 64;
    const int tid = threadIdx.x;
    __shared__ float D[64 * 65];
    __shared__ float DT[64 * 64];
    __shared__ float invd[64];
    __shared__ float y1s[64], y2s[64];
    __shared__ float px[NA], py[NA], pz[NA], s2s[NA];

    if (j == 0) {
#pragma unroll
        for (int e = 0; e < 2; e++) {
            int i = e * 256 + tid;
            px[i] = pos[((size_t)b * NA + i) * 3 + 0];
            py[i] = pos[((size_t)b * NA + i) * 3 + 1];
            pz[i] = pos[((size_t)b * NA + i) * 3 + 2];
            float s = sigA[b * NA + i];
            s2s[i] = s * s;
        }
        __syncthreads();
    }

#pragma unroll
    for (int e = 0; e < 16; e++) {
        int f = e * 256 + tid;
        int rr = f >> 6, cc = f & 63;
        float v;
        if (j == 0) {
            if (rr == cc) v = diagA[b * NA + rr];
            else v = pair_val(px[rr]-px[cc], py[rr]-py[cc], pz[rr]-pz[cc], s2s[rr], s2s[cc]);
        } else {
            v = Cb[(size_t)(jb + rr) * NA + jb + cc];
        }
        D[rr * 65 + cc] = v;
    }

    const int h = m >> 1;
    const int r0 = q ? h : 0;
    const int nr = q ? (m - h) : h;
    const int r = tid - 32;
    const bool hasrow = (r >= 0 && r < nr);
    const int grow = jb + 64 + r0 + r;
    float rv[64];
    if (hasrow) {
        if (j == 0) {
#pragma unroll
            for (int k = 0; k < 64; k++)
                rv[k] = pair_val(px[grow]-px[k], py[grow]-py[k], pz[grow]-pz[k],
                                 s2s[grow], s2s[k]);
        } else {
            const float4* rp = (const float4*)(Cb + (size_t)grow * NA + jb);
#pragma unroll
            for (int qq = 0; qq < 16; qq++) {
                float4 v = rp[qq];
                rv[4*qq] = v.x; rv[4*qq+1] = v.y; rv[4*qq+2] = v.z; rv[4*qq+3] = v.w;
            }
        }
    }
    __syncthreads();

    if (tid < 64) {
        const int t = tid;
        float cl[64];
#pragma unroll
        for (int i = 0; i < 64; i++) cl[i] = (i >= t) ? D[i * 65 + t] : D[t * 65 + i];
#pragma unroll
        for (int k = 0; k < 64; k++) {
            float pivot = rl(cl[k], k);
            float invp = 1.0f / pivot;
            float factor = (t > k) ? (cl[k] * invp) : 0.0f;
#pragma unroll
            for (int i = k + 1; i < 64; i++) {
                float bc = rl(cl[i], k);
                cl[i] -= bc * factor;
            }
        }
        float rs = 1.0f / sqrtf(cl[t]);
        invd[t] = rs;
#pragma unroll
        for (int i = 0; i < 64; i++)
            if (i >= t) D[i * 65 + t] = cl[i] * rs;

        // ---- fused forward substitution: solve L_jj y = r_j for both RHS.
        float v1 = r1[(size_t)b * NA + jb + t];
        float v2 = r2[(size_t)b * NA + jb + t];
#pragma unroll
        for (int k = 0; k < 64; k++) {
            float rsk = rl(rs, k);
            float y1k = rl(v1, k) * rsk;
            float y2k = rl(v2, k) * rsk;
            if (t == k) {
                y1s[t] = y1k; y2s[t] = y2k;
                if (q == 0) {
                    r1[(size_t)b * NA + jb + t] = y1k;
                    r2[(size_t)b * NA + jb + t] = y2k;
                }
            }
            float lv = (t > k) ? D[t * 65 + k] : 0.f;
            v1 -= lv * y1k;
            v2 -= lv * y2k;
        }
    }
    __syncthreads();

#pragma unroll
    for (int e = 0; e < 16; e++) {
        int f = e * 256 + tid;
        int row = f >> 6, cc = f & 63;
        float v = D[row * 65 + cc];
        DT[row * 64 + cc] = (cc < row) ? v : 0.f;
        if (q == 0 && cc <= row) Cb[(size_t)(jb + row) * NA + jb + cc] = v;
    }
    __syncthreads();

    if (hasrow) {
#pragma unroll
        for (int k = 0; k < 64; k++) {
            float acc = rv[k];
            const float4* Lr = (const float4*)(DT + k * 64);
            const int k4 = k >> 2;
#pragma unroll
            for (int t4 = 0; t4 < k4; t4++) {
                float4 Lv = Lr[t4];
                acc -= Lv.x * rv[4*t4] + Lv.y * rv[4*t4+1] + Lv.z * rv[4*t4+2] + Lv.w * rv[4*t4+3];
            }
#pragma unroll
            for (int tt = k4 * 4; tt < k; tt++) acc -= DT[k * 64 + tt] * rv[tt];
            rv[k] = acc * invd[k];
        }
        float4* rp = (float4*)(Cb + (size_t)grow * NA + jb);
#pragma unroll
        for (int qq = 0; qq < 16; qq++)
            rp[qq] = make_float4(rv[4*qq], rv[4*qq+1], rv[4*qq+2], rv[4*qq+3]);

        // ---- fused forward update: r[grow] -= L_row . y_j (both RHS).
        float a1 = 0.f, a2 = 0.f;
#pragma unroll
        for (int k = 0; k < 64; k++) {
            a1 = fmaf(rv[k], y1s[k], a1);
            a2 = fmaf(rv[k], y2s[k], a2);
        }
        r1[(size_t)b * NA + grow] -= a1;
        r2[(size_t)b * NA + grow] -= a2;
    }
}

// ------------------------------------------- K3: trailing update (j<=4)
// Round-15 (retry): round-13 structure + explicit register double-buffering of
// the k-pair operands (two NAMED sets, no runtime indexing -> no scratch). Next
// pair's 16 ds_read_b64 issue before current pair's 128 FMAs, guaranteeing
// LDS latency is covered at fixed occupancy. Reads at k=64/65 hit the
// stride-66 pad (exists, never used in FMA).
template<bool GEN>
__global__ void __launch_bounds__(256, 2) k_trail(float* __restrict__ C,
                                                  const float* __restrict__ pos,
                                                  const float* __restrict__ sigA,
                                                  const float* __restrict__ diagA,
                                                  const int j) {
    const int b = blockIdx.y;
    float* __restrict__ Cb = C + (size_t)b * NN;
    const int jb = j * 64;
    const int m = NA - jb - 64;
    int t = blockIdx.x;
    int RI = 0;
    while (t >= RI + 1) { t -= RI + 1; RI++; }
    const int RJ = t;
    const int RB = RI * 128, CB = RJ * 128;
    const int vr = min(128, m - RB);
    const int vc = min(128, m - CB);
    const int tid = threadIdx.x;
    const int rg = tid >> 4, cg = tid & 15;

    __shared__ float As[128 * 66];
    __shared__ float Bs[128 * 66];

    v2f ac2[8][8];

    if (GEN) {
        __shared__ float pAx[128], pAy[128], pAz[128], sA[128], dA[128];
        __shared__ float pBx[128], pBy[128], pBz[128], sB[128];
        if (tid < 128) {
            if (RB + tid < m) {
                int ga = b * NA + jb + 64 + RB + tid;
                pAx[tid] = pos[(size_t)ga * 3 + 0];
                pAy[tid] = pos[(size_t)ga * 3 + 1];
                pAz[tid] = pos[(size_t)ga * 3 + 2];
                float s = sigA[ga]; sA[tid] = s * s;
                dA[tid] = diagA[ga];
            }
        } else {
            int u = tid - 128;
            if (CB + u < m) {
                int gb = b * NA + jb + 64 + CB + u;
                pBx[u] = pos[(size_t)gb * 3 + 0];
                pBy[u] = pos[(size_t)gb * 3 + 1];
                pBz[u] = pos[(size_t)gb * 3 + 2];
                float s = sigA[gb]; sB[u] = s * s;
            }
        }
        __syncthreads();
#pragma unroll
        for (int rr = 0; rr < 8; rr++) {
            int row = rg * 8 + rr;
#pragma unroll
            for (int cc = 0; cc < 8; cc++) {
                int col = cg + 16 * cc;
                float iv;
                if (RB + row == CB + col)
                    iv = dA[row];
                else
                    iv = pair_val(pAx[row]-pBx[col], pAy[row]-pBy[col],
                                  pAz[row]-pBz[col], sA[row], sB[col]);
                ac2[rr][cc].x = iv;
                ac2[rr][cc].y = 0.f;
            }
        }
        __syncthreads();
    } else {
        const int GRB = jb + 64 + RB, GCB = jb + 64 + CB;
#pragma unroll
        for (int rr = 0; rr < 8; rr++) {
            int row = rg * 8 + rr;
#pragma unroll
            for (int cc = 0; cc < 8; cc++) {
                int col = cg + 16 * cc;
                ac2[rr][cc].x = (row < vr && col < vc)
                    ? Cb[(size_t)(GRB + row) * NA + GCB + col] : 0.f;
                ac2[rr][cc].y = 0.f;
            }
        }
    }

    const float* Pan = Cb + (size_t)(jb + 64) * NA + jb;
#pragma unroll
    for (int e = 0; e < 8; e++) {
        int f = e * 256 + tid;
        int row = f >> 4, s = f & 15;
        float4 v = make_float4(0.f, 0.f, 0.f, 0.f);
        if (row < vr) v = *(const float4*)(Pan + (size_t)(RB + row) * NA + s * 4);
        As[row * 66 + s * 4 + 0] = v.x;
        As[row * 66 + s * 4 + 1] = v.y;
        As[row * 66 + s * 4 + 2] = v.z;
        As[row * 66 + s * 4 + 3] = v.w;
        float4 u = make_float4(0.f, 0.f, 0.f, 0.f);
        if (row < vc) u = *(const float4*)(Pan + (size_t)(CB + row) * NA + s * 4);
        Bs[row * 66 + s * 4 + 0] = u.x;
        Bs[row * 66 + s * 4 + 1] = u.y;
        Bs[row * 66 + s * 4 + 2] = u.z;
        Bs[row * 66 + s * 4 + 3] = u.w;
    }
    __syncthreads();

    // register double-buffered k-loop: sets A and B alternate (4 k per iter)
    v2f aiA[8], bjA[8], aiB[8], bjB[8];
#pragma unroll
    for (int rr = 0; rr < 8; rr++) aiA[rr] = *(const v2f*)&As[(rg * 8 + rr) * 66 + 0];
#pragma unroll
    for (int cc = 0; cc < 8; cc++) bjA[cc] = *(const v2f*)&Bs[(cg + 16 * cc) * 66 + 0];

#pragma unroll 1
    for (int k = 0; k < 64; k += 4) {
        // prefetch pair k+2 into set B
#pragma unroll
        for (int rr = 0; rr < 8; rr++) aiB[rr] = *(const v2f*)&As[(rg * 8 + rr) * 66 + k + 2];
#pragma unroll
        for (int cc = 0; cc < 8; cc++) bjB[cc] = *(const v2f*)&Bs[(cg + 16 * cc) * 66 + k + 2];
        // FMA with set A (pair k)
#pragma unroll
        for (int rr = 0; rr < 8; rr++)
#pragma unroll
            for (int cc = 0; cc < 8; cc++) {
                ac2[rr][cc].x = fmaf(-aiA[rr].x, bjA[cc].x, ac2[rr][cc].x);
                ac2[rr][cc].y = fmaf(-aiA[rr].y, bjA[cc].y, ac2[rr][cc].y);
            }
        // prefetch pair k+4 into set A (k=60 -> reads pad cols 64/65, unused)
#pragma unroll
        for (int rr = 0; rr < 8; rr++) aiA[rr] = *(const v2f*)&As[(rg * 8 + rr) * 66 + k + 4];
#pragma unroll
        for (int cc = 0; cc < 8; cc++) bjA[cc] = *(const v2f*)&Bs[(cg + 16 * cc) * 66 + k + 4];
        // FMA with set B (pair k+2)
#pragma unroll
        for (int rr = 0; rr < 8; rr++)
#pragma unroll
            for (int cc = 0; cc < 8; cc++) {
                ac2[rr][cc].x = fmaf(-aiB[rr].x, bjB[cc].x, ac2[rr][cc].x);
                ac2[rr][cc].y = fmaf(-aiB[rr].y, bjB[cc].y, ac2[rr][cc].y);
            }
    }

    const int GRB = jb + 64 + RB, GCB = jb + 64 + CB;
#pragma unroll
    for (int rr = 0; rr < 8; rr++) {
        int row = rg * 8 + rr;
        if (row < vr) {
#pragma unroll
            for (int cc = 0; cc < 8; cc++) {
                int col = cg + 16 * cc;
                if (col < vc)
                    Cb[(size_t)(GRB + row) * NA + GCB + col] = ac2[rr][cc].x + ac2[rr][cc].y;
            }
        }
    }
}

// ------------------------------------------- K3b: fused tail (j=5,6,7) — round-5 proven
__global__ void __launch_bounds__(256, 1) k_tail(float* __restrict__ C,
                                                 float* __restrict__ r1,
                                                 float* __restrict__ r2) {
    const int b = blockIdx.x;
    float* __restrict__ Cb = C + (size_t)b * NN;
    const int tid = threadIdx.x;
    __shared__ float T[TS * TSTR];
    __shared__ float invd[64], y1s[64], y2s[64];

    for (int f = tid; f < TS * TS; f += 256) {
        int row = f / TS, c = f - row * TS;
        T[row * TSTR + c] = Cb[(size_t)(TB + row) * NA + TB + c];
    }
    __syncthreads();

#pragma unroll 1
    for (int p = 0; p < 3; p++) {
        const int pb = p * 64;
        const int msub = TS - pb - 64;

        if (tid < 64) {
            const int t = tid;
            float cl[64];
#pragma unroll
            for (int i = 0; i < 64; i++)
                cl[i] = (i >= t) ? T[(pb + i) * TSTR + pb + t]
                                 : T[(pb + t) * TSTR + pb + i];
#pragma unroll
            for (int k = 0; k < 64; k++) {
                float pivot = rl(cl[k], k);
                float invp = 1.0f / pivot;
                float factor = (t > k) ? (cl[k] * invp) : 0.0f;
#pragma unroll
                for (int i = k + 1; i < 64; i++) {
                    float bc = rl(cl[i], k);
                    cl[i] -= bc * factor;
                }
            }
            float rs = 1.0f / sqrtf(cl[t]);
            invd[t] = rs;
#pragma unroll
            for (int i = 0; i < 64; i++) {
                float lv = cl[i] * rs;
                if (i >= t) T[(pb + i) * TSTR + pb + t] = lv;   // L (column t)
                if (i > t)  T[(pb + t) * TSTR + pb + i] = lv;   // L^T (row t)
            }
            // fused forward substitution, both RHS
            float v1 = r1[(size_t)b * NA + TB + pb + t];
            float v2 = r2[(size_t)b * NA + TB + pb + t];
#pragma unroll
            for (int k = 0; k < 64; k++) {
                float rsk = rl(rs, k);
                float y1k = rl(v1, k) * rsk;
                float y2k = rl(v2, k) * rsk;
                if (t == k) {
                    y1s[t] = y1k; y2s[t] = y2k;
                    r1[(size_t)b * NA + TB + pb + t] = y1k;
                    r2[(size_t)b * NA + TB + pb + t] = y2k;
                }
                float lv = (t > k) ? T[(pb + t) * TSTR + pb + k] : 0.f;
                v1 -= lv * y1k;
                v2 -= lv * y2k;
            }
        }
        __syncthreads();

        if (msub > 0) {
            if (tid < msub) {
                const int row_l = pb + 64 + tid;
                float rv[64];
#pragma unroll
                for (int k = 0; k < 64; k++) rv[k] = T[row_l * TSTR + pb + k];
#pragma unroll
                for (int k = 0; k < 64; k++) {
                    float yk = rv[k] * invd[k];
                    rv[k] = yk;
                    const float* LTrow = &T[(pb + k) * TSTR + pb];
#pragma unroll
                    for (int i = k + 1; i < 64; i++)
                        rv[i] -= LTrow[i] * yk;
                }
#pragma unroll
                for (int k = 0; k < 64; k++) T[row_l * TSTR + pb + k] = rv[k];
                float a1 = 0.f, a2 = 0.f;
#pragma unroll
                for (int k = 0; k < 64; k++) {
                    a1 = fmaf(rv[k], y1s[k], a1);
                    a2 = fmaf(rv[k], y2s[k], a2);
                }
                r1[(size_t)b * NA + TB + row_l] -= a1;
                r2[(size_t)b * NA + TB + row_l] -= a2;
            }
            __syncthreads();

            const int rbase = pb + 64;
            if (p == 0) {
                // 128x128 trailing, 8x8 per thread
                const int rg = tid >> 4, cg = tid & 15;
                float acc[8][8];
#pragma unroll
                for (int rr = 0; rr < 8; rr++)
#pragma unroll
                    for (int cc = 0; cc < 8; cc++)
                        acc[rr][cc] = T[(rbase + rg * 8 + rr) * TSTR + rbase + cg * 8 + cc];
#pragma unroll 4
                for (int k = 0; k < 64; k++) {
                    float ai[8], bj[8];
#pragma unroll
                    for (int rr = 0; rr < 8; rr++)
                        ai[rr] = T[(rbase + rg * 8 + rr) * TSTR + pb + k];
#pragma unroll
                    for (int cc = 0; cc < 8; cc++)
                        bj[cc] = T[(rbase + cg * 8 + cc) * TSTR + pb + k];
#pragma unroll
                    for (int rr = 0; rr < 8; rr++)
#pragma unroll
                        for (int cc = 0; cc < 8; cc++)
                            acc[rr][cc] = fmaf(-ai[rr], bj[cc], acc[rr][cc]);
                }
#pragma unroll
                for (int rr = 0; rr < 8; rr++)
#pragma unroll
                    for (int cc = 0; cc < 8; cc++)
                        T[(rbase + rg * 8 + rr) * TSTR + rbase + cg * 8 + cc] = acc[rr][cc];
            } else {
                // 64x64 trailing, 4x4 per thread
                const int rg = tid >> 4, cg = tid & 15;
                float acc[4][4];
#pragma unroll
                for (int rr = 0; rr < 4; rr++)
#pragma unroll
                    for (int cc = 0; cc < 4; cc++)
                        acc[rr][cc] = T[(rbase + rg * 4 + rr) * TSTR + rbase + cg * 4 + cc];
#pragma unroll 4
                for (int k = 0; k < 64; k++) {
                    float ai[4], bj[4];
#pragma unroll
                    for (int rr = 0; rr < 4; rr++)
                        ai[rr] = T[(rbase + rg * 4 + rr) * TSTR + pb + k];
#pragma unroll
                    for (int cc = 0; cc < 4; cc++)
                        bj[cc] = T[(rbase + cg * 4 + cc) * TSTR + pb + k];
#pragma unroll
                    for (int rr = 0; rr < 4; rr++)
#pragma unroll
                        for (int cc = 0; cc < 4; cc++)
                            acc[rr][cc] = fmaf(-ai[rr], bj[cc], acc[rr][cc]);
                }
#pragma unroll
                for (int rr = 0; rr < 4; rr++)
#pragma unroll
                    for (int cc = 0; cc < 4; cc++)
                        T[(rbase + rg * 4 + rr) * TSTR + rbase + cg * 4 + cc] = acc[rr][cc];
            }
        }
        __syncthreads();
    }

    for (int f = tid; f < TS * TS; f += 256) {
        int row = f / TS, c = f - row * TS;
        Cb[(size_t)(TB + row) * NA + TB + c] = T[row * TSTR + c];
    }
}

// ------------------------------------------- K4: backward-only solve (grid = B x 2)
__global__ void __launch_bounds__(512, 1) k_back(const float* __restrict__ C,
                                                 float* __restrict__ r1g,
                                                 float* __restrict__ r2g) {
    const int b = blockIdx.x;
    const int rhs = blockIdx.y;
    const float* Cb = C + (size_t)b * NN;
    const int tid = threadIdx.x;
    __shared__ float D[64 * 65];
    __shared__ float r[NA];
    __shared__ float pb[4][NA];

    float* rg = rhs ? r2g : r1g;
    r[tid] = rg[(size_t)b * NA + tid];

    const int ii = tid & 127;
    const int gg = tid >> 7;
    for (int j = 7; j >= 0; j--) {
        const int jb = j * 64;
        __syncthreads();
#pragma unroll
        for (int e = 0; e < 8; e++) {
            int f = e * 512 + tid;
            int row = f >> 6, cc = f & 63;
            D[row * 65 + cc] = Cb[(size_t)(jb + row) * NA + jb + cc];
        }
        __syncthreads();
        if (tid < 64) {
            float val = r[jb + tid];
            float idg = 1.0f / D[tid * 65 + tid];
#pragma unroll
            for (int k = 63; k >= 0; k--) {
                float xk = rl(val, k) * rl(idg, k);
                if (tid == k) r[jb + k] = xk;
                float lv = (tid < k) ? D[k * 65 + tid] : 0.f;
                val -= lv * xk;
            }
        }
        __syncthreads();
        if (jb > 0) {
            const int nf4 = jb >> 2;
            float4 s1 = make_float4(0.f, 0.f, 0.f, 0.f);
            if (ii < nf4) {
#pragma unroll
                for (int gq = 0; gq < 16; gq++) {
                    int g = jb + gg * 16 + gq;
                    float x1 = r[g];
                    float4 Lv = *(const float4*)(Cb + (size_t)g * NA + ii * 4);
                    s1.x += Lv.x * x1; s1.y += Lv.y * x1; s1.z += Lv.z * x1; s1.w += Lv.w * x1;
                }
            }
            *(float4*)(&pb[gg][ii * 4]) = s1;
            __syncthreads();
            if (tid < jb)
                r[tid] -= pb[0][tid] + pb[1][tid] + pb[2][tid] + pb[3][tid];
        }
    }
    __syncthreads();

    rg[(size_t)b * NA + tid] = r[tid];
}

// ------------------------------------------- K5: mu, q, energy from x1, x2
__global__ void __launch_bounds__(512, 1) k_final(const float* __restrict__ x1,
                                                  const float* __restrict__ x2,
                                                  const float* __restrict__ chiA,
                                                  const float* __restrict__ Qtot,
                                                  float* __restrict__ out, int B) {
    const int b = blockIdx.x;
    const int tid = threadIdx.x;
    __shared__ float red[16];
    __shared__ float muS;

    float v1 = x1[(size_t)b * NA + tid];
    float v2 = x2[(size_t)b * NA + tid];

    float s1p = v1, s2p = v2;
#pragma unroll
    for (int off = 1; off < 64; off <<= 1) {
        s1p += __shfl_xor(s1p, off);
        s2p += __shfl_xor(s2p, off);
    }
    if ((tid & 63) == 0) { red[tid >> 6] = s1p; red[8 + (tid >> 6)] = s2p; }
    __syncthreads();
    if (tid == 0) {
        float s1 = 0.f, s2 = 0.f;
#pragma unroll
        for (int wv = 0; wv < 8; wv++) { s1 += red[wv]; s2 += red[8 + wv]; }
        muS = -(Qtot[b] + s1) / s2;
    }
    __syncthreads();
    float mu = muS;
    float qv = -v1 - mu * v2;
    out[B + (size_t)b * NA + tid] = qv;

    float eacc = chiA[b * NA + tid] * qv;
#pragma unroll
    for (int off = 1; off < 64; off <<= 1) eacc += __shfl_xor(eacc, off);
    __syncthreads();
    if ((tid & 63) == 0) red[tid >> 6] = eacc;
    __syncthreads();
    if (tid == 0) {
        float e = 0.f;
#pragma unroll
        for (int wv = 0; wv < 8; wv++) e += red[wv];
        out[b] = 0.5f * e - 0.5f * mu * Qtot[b];
    }
}

// ---------------------------------------------------------------- host launch
extern "C" void kernel_launch(void* const* d_in, const int* in_sizes, int n_in,
                              void* d_out, int out_size, void* d_ws, size_t ws_size,
                              hipStream_t stream) {
    const int B = in_sizes[3];          // 128 molecules
    const int N = in_sizes[2];          // 65536 atoms
    const float* feats = (const float*)d_in[0];
    const float* pos   = (const float*)d_in[1];
    const int*   type  = (const int*)d_in[2];
    const float* Qt    = (const float*)d_in[3];
    const float* w     = (const float*)d_in[4];
    const float* hard  = (const float*)d_in[5];
    const float* sig   = (const float*)d_in[6];
    float* out = (float*)d_out;
    float* ws  = (float*)d_ws;

    float* C    = ws;                       // B * 512 * 512
    float* chi  = ws + (size_t)B * NN;      // N
    float* diag = chi + N;                  // N
    float* sigA = diag + N;                 // N
    float* r1   = sigA + N;                 // N (rhs1: chi -> y -> x1)
    float* r2   = r1 + N;                   // N (rhs2: 1   -> y -> x2)

    k_pre<<<(N + 255) / 256, 256, 0, stream>>>(feats, w, type, hard, sig,
                                               chi, diag, sigA, r1, r2, N);

    static const int tilesJ[5] = {10, 6, 6, 3, 3};
    for (int j = 0; j < 5; j++) {
        k_panel<<<dim3(2, B), 256, 0, stream>>>(pos, sigA, diag, C, r1, r2, j);
        if (j == 0)
            k_trail<true><<<dim3(tilesJ[j], B), 256, 0, stream>>>(C, pos, sigA, diag, j);
        else
            k_trail<false><<<dim3(tilesJ[j], B), 256, 0, stream>>>(C, pos, sigA, diag, j);
    }
    k_tail<<<B, 256, 0, stream>>>(C, r1, r2);
    k_back<<<dim3(B, 2), 512, 0, stream>>>(C, r1, r2);
    k_final<<<B, 512, 0, stream>>>(r1, r2, chi, Qt, out, B);
}

// Round 9
// 727.797 us; speedup vs baseline: 1.1075x; 1.0032x over previous
//
#include <hip/hip_runtime.h>
#include <math.h>

#define NA 512
#define NN (NA*NA)
#define COULOMB 14.399645478425668f
#define SQRT_PI 1.7724538509055160273f

// tail-fusion region: last 192 rows/cols handled by k_tail in LDS
#define TB 320
#define TS 192
#define TSTR 193

typedef float v2f __attribute__((ext_vector_type(2)));

__device__ __forceinline__ float rl(float x, int lane) {
    return __int_as_float(__builtin_amdgcn_readlane(__float_as_int(x), lane));
}

__device__ __forceinline__ float pair_val(float dx, float dy, float dz,
                                          float s2i, float s2k) {
    float d2 = dx*dx + dy*dy + dz*dz;
    float rinv = rsqrtf(d2);
    return COULOMB * erff(d2 * rinv * rsqrtf(2.f * (s2i + s2k))) * rinv;
}

// ---------------------------------------------------------------- K1: per-atom
// Also initializes the two RHS vectors: r1 = chi, r2 = 1.
__global__ void k_pre(const float* __restrict__ feats, const float* __restrict__ w,
                      const int* __restrict__ type, const float* __restrict__ hard,
                      const float* __restrict__ sigma,
                      float* __restrict__ chi, float* __restrict__ diag,
                      float* __restrict__ sigA,
                      float* __restrict__ r1, float* __restrict__ r2, int N) {
    __shared__ float wl[64];
    int tid = threadIdx.x;
    if (tid < 64) wl[tid] = w[tid];
    __syncthreads();
    int i = blockIdx.x * 256 + tid;
    if (i >= N) return;
    const float4* fp = (const float4*)(feats + (size_t)i * 64);
    float acc = 0.f;
#pragma unroll
    for (int q = 0; q < 16; q++) {
        float4 v = fp[q];
        acc += v.x * wl[4*q] + v.y * wl[4*q+1] + v.z * wl[4*q+2] + v.w * wl[4*q+3];
    }
    chi[i] = acc;
    r1[i] = acc;
    r2[i] = 1.0f;
    int t = type[i];
    float s = sigma[t];
    float h = hard[t];
    sigA[i] = s;
    diag[i] = h * h + COULOMB / (SQRT_PI * s);
}

// ------------------------------------------- K2: diag factor + split panel trsm (j<=4)
// Forward substitution for BOTH RHS fused here (round-11 proven).
__global__ void __launch_bounds__(256, 1) k_panel(const float* __restrict__ pos,
                                                  const float* __restrict__ sigA,
                                                  const float* __restrict__ diagA,
                                                  float* __restrict__ C,
                                                  float* __restrict__ r1,
                                                  float* __restrict__ r2, const int j) {
    const int q = blockIdx.x;
    const int b = blockIdx.y;
    float* __restrict__ Cb = C + (size_t)b * NN;
    const int jb = j * 64;
    const int m = NA - jb - 64;
    const int tid = threadIdx.x;
    __shared__ float D[64 * 65];
    __shared__ float DT[64 * 64];
    __shared__ float invd[64];
    __shared__ float y1s[64], y2s[64];
    __shared__ float px[NA], py[NA], pz[NA], s2s[NA];

    if (j == 0) {
#pragma unroll
        for (int e = 0; e < 2; e++) {
            int i = e * 256 + tid;
            px[i] = pos[((size_t)b * NA + i) * 3 + 0];
            py[i] = pos[((size_t)b * NA + i) * 3 + 1];
            pz[i] = pos[((size_t)b * NA + i) * 3 + 2];
            float s = sigA[b * NA + i];
            s2s[i] = s * s;
        }
        __syncthreads();
    }

#pragma unroll
    for (int e = 0; e < 16; e++) {
        int f = e * 256 + tid;
        int rr = f >> 6, cc = f & 63;
        float v;
        if (j == 0) {
            if (rr == cc) v = diagA[b * NA + rr];
            else v = pair_val(px[rr]-px[cc], py[rr]-py[cc], pz[rr]-pz[cc], s2s[rr], s2s[cc]);
        } else {
            v = Cb[(size_t)(jb + rr) * NA + jb + cc];
        }
        D[rr * 65 + cc] = v;
    }

    const int h = m >> 1;
    const int r0 = q ? h : 0;
    const int nr = q ? (m - h) : h;
    const int r = tid - 32;
    const bool hasrow = (r >= 0 && r < nr);
    const int grow = jb + 64 + r0 + r;
    float rv[64];
    if (hasrow) {
        if (j == 0) {
#pragma unroll
            for (int k = 0; k < 64; k++)
                rv[k] = pair_val(px[grow]-px[k], py[grow]-py[k], pz[grow]-pz[k],
                                 s2s[grow], s2s[k]);
        } else {
            const float4* rp = (const float4*)(Cb + (size_t)grow * NA + jb);
#pragma unroll
            for (int qq = 0; qq < 16; qq++) {
                float4 v = rp[qq];
                rv[4*qq] = v.x; rv[4*qq+1] = v.y; rv[4*qq+2] = v.z; rv[4*qq+3] = v.w;
            }
        }
    }
    __syncthreads();

    if (tid < 64) {
        const int t = tid;
        float cl[64];
#pragma unroll
        for (int i = 0; i < 64; i++) cl[i] = (i >= t) ? D[i * 65 + t] : D[t * 65 + i];
#pragma unroll
        for (int k = 0; k < 64; k++) {
            float pivot = rl(cl[k], k);
            float invp = 1.0f / pivot;
            float factor = (t > k) ? (cl[k] * invp) : 0.0f;
#pragma unroll
            for (int i = k + 1; i < 64; i++) {
                float bc = rl(cl[i], k);
                cl[i] -= bc * factor;
            }
        }
        float rs = 1.0f / sqrtf(cl[t]);
        invd[t] = rs;
#pragma unroll
        for (int i = 0; i < 64; i++)
            if (i >= t) D[i * 65 + t] = cl[i] * rs;

        // ---- fused forward substitution: solve L_jj y = r_j for both RHS.
        float v1 = r1[(size_t)b * NA + jb + t];
        float v2 = r2[(size_t)b * NA + jb + t];
#pragma unroll
        for (int k = 0; k < 64; k++) {
            float rsk = rl(rs, k);
            float y1k = rl(v1, k) * rsk;
            float y2k = rl(v2, k) * rsk;
            if (t == k) {
                y1s[t] = y1k; y2s[t] = y2k;
                if (q == 0) {
                    r1[(size_t)b * NA + jb + t] = y1k;
                    r2[(size_t)b * NA + jb + t] = y2k;
                }
            }
            float lv = (t > k) ? D[t * 65 + k] : 0.f;
            v1 -= lv * y1k;
            v2 -= lv * y2k;
        }
    }
    __syncthreads();

#pragma unroll
    for (int e = 0; e < 16; e++) {
        int f = e * 256 + tid;
        int row = f >> 6, cc = f & 63;
        float v = D[row * 65 + cc];
        DT[row * 64 + cc] = (cc < row) ? v : 0.f;
        if (q == 0 && cc <= row) Cb[(size_t)(jb + row) * NA + jb + cc] = v;
    }
    __syncthreads();

    if (hasrow) {
#pragma unroll
        for (int k = 0; k < 64; k++) {
            float acc = rv[k];
            const float4* Lr = (const float4*)(DT + k * 64);
            const int k4 = k >> 2;
#pragma unroll
            for (int t4 = 0; t4 < k4; t4++) {
                float4 Lv = Lr[t4];
                acc -= Lv.x * rv[4*t4] + Lv.y * rv[4*t4+1] + Lv.z * rv[4*t4+2] + Lv.w * rv[4*t4+3];
            }
#pragma unroll
            for (int tt = k4 * 4; tt < k; tt++) acc -= DT[k * 64 + tt] * rv[tt];
            rv[k] = acc * invd[k];
        }
        float4* rp = (float4*)(Cb + (size_t)grow * NA + jb);
#pragma unroll
        for (int qq = 0; qq < 16; qq++)
            rp[qq] = make_float4(rv[4*qq], rv[4*qq+1], rv[4*qq+2], rv[4*qq+3]);

        // ---- fused forward update: r[grow] -= L_row . y_j (both RHS).
        float a1 = 0.f, a2 = 0.f;
#pragma unroll
        for (int k = 0; k < 64; k++) {
            a1 = fmaf(rv[k], y1s[k], a1);
            a2 = fmaf(rv[k], y2s[k], a2);
        }
        r1[(size_t)b * NA + grow] -= a1;
        r2[(size_t)b * NA + grow] -= a2;
    }
}

// ------------------------------------------- K3: trailing update (j<=4)
// Round-17: SPILL FIX. Round-4's v2f ac2[8][8] needed 128 acc VGPRs but the
// kernel reported only 108 -> ~40 floats lived in scratch, reloaded every
// k-iter (the hidden cost behind 55% VALUBusy / 6x-over-FMA time). Keep the
// proven stride-66 + ds_read_b64 operand staging; accumulator back to scalar
// acc[8][8] (64 VGPR) with two dependent FMAs per k-pair. 64 indep chains of
// ILP is ample; register budget ~95 -> no scratch.
template<bool GEN>
__global__ void __launch_bounds__(256, 2) k_trail(float* __restrict__ C,
                                                  const float* __restrict__ pos,
                                                  const float* __restrict__ sigA,
                                                  const float* __restrict__ diagA,
                                                  const int j) {
    const int b = blockIdx.y;
    float* __restrict__ Cb = C + (size_t)b * NN;
    const int jb = j * 64;
    const int m = NA - jb - 64;
    int t = blockIdx.x;
    int RI = 0;
    while (t >= RI + 1) { t -= RI + 1; RI++; }
    const int RJ = t;
    const int RB = RI * 128, CB = RJ * 128;
    const int vr = min(128, m - RB);
    const int vc = min(128, m - CB);
    const int tid = threadIdx.x;
    const int rg = tid >> 4, cg = tid & 15;

    __shared__ float As[128 * 66];
    __shared__ float Bs[128 * 66];

    float acc[8][8];

    if (GEN) {
        __shared__ float pAx[128], pAy[128], pAz[128], sA[128], dA[128];
        __shared__ float pBx[128], pBy[128], pBz[128], sB[128];
        if (tid < 128) {
            if (RB + tid < m) {
                int ga = b * NA + jb + 64 + RB + tid;
                pAx[tid] = pos[(size_t)ga * 3 + 0];
                pAy[tid] = pos[(size_t)ga * 3 + 1];
                pAz[tid] = pos[(size_t)ga * 3 + 2];
                float s = sigA[ga]; sA[tid] = s * s;
                dA[tid] = diagA[ga];
            }
        } else {
            int u = tid - 128;
            if (CB + u < m) {
                int gb = b * NA + jb + 64 + CB + u;
                pBx[u] = pos[(size_t)gb * 3 + 0];
                pBy[u] = pos[(size_t)gb * 3 + 1];
                pBz[u] = pos[(size_t)gb * 3 + 2];
                float s = sigA[gb]; sB[u] = s * s;
            }
        }
        __syncthreads();
#pragma unroll
        for (int rr = 0; rr < 8; rr++) {
            int row = rg * 8 + rr;
#pragma unroll
            for (int cc = 0; cc < 8; cc++) {
                int col = cg + 16 * cc;
                if (RB + row == CB + col)
                    acc[rr][cc] = dA[row];
                else
                    acc[rr][cc] = pair_val(pAx[row]-pBx[col], pAy[row]-pBy[col],
                                           pAz[row]-pBz[col], sA[row], sB[col]);
            }
        }
        __syncthreads();
    } else {
        const int GRB = jb + 64 + RB, GCB = jb + 64 + CB;
#pragma unroll
        for (int rr = 0; rr < 8; rr++) {
            int row = rg * 8 + rr;
#pragma unroll
            for (int cc = 0; cc < 8; cc++) {
                int col = cg + 16 * cc;
                acc[rr][cc] = (row < vr && col < vc)
                    ? Cb[(size_t)(GRB + row) * NA + GCB + col] : 0.f;
            }
        }
    }

    const float* Pan = Cb + (size_t)(jb + 64) * NA + jb;
#pragma unroll
    for (int e = 0; e < 8; e++) {
        int f = e * 256 + tid;
        int row = f >> 4, s = f & 15;
        float4 v = make_float4(0.f, 0.f, 0.f, 0.f);
        if (row < vr) v = *(const float4*)(Pan + (size_t)(RB + row) * NA + s * 4);
        As[row * 66 + s * 4 + 0] = v.x;
        As[row * 66 + s * 4 + 1] = v.y;
        As[row * 66 + s * 4 + 2] = v.z;
        As[row * 66 + s * 4 + 3] = v.w;
        float4 u = make_float4(0.f, 0.f, 0.f, 0.f);
        if (row < vc) u = *(const float4*)(Pan + (size_t)(CB + row) * NA + s * 4);
        Bs[row * 66 + s * 4 + 0] = u.x;
        Bs[row * 66 + s * 4 + 1] = u.y;
        Bs[row * 66 + s * 4 + 2] = u.z;
        Bs[row * 66 + s * 4 + 3] = u.w;
    }
    __syncthreads();

#pragma unroll 2
    for (int k = 0; k < 64; k += 2) {
        v2f ai2[8], bj2[8];
#pragma unroll
        for (int rr = 0; rr < 8; rr++)
            ai2[rr] = *(const v2f*)&As[(rg * 8 + rr) * 66 + k];
#pragma unroll
        for (int cc = 0; cc < 8; cc++)
            bj2[cc] = *(const v2f*)&Bs[(cg + 16 * cc) * 66 + k];
#pragma unroll
        for (int rr = 0; rr < 8; rr++)
#pragma unroll
            for (int cc = 0; cc < 8; cc++)
                acc[rr][cc] = fmaf(-ai2[rr].y, bj2[cc].y,
                                   fmaf(-ai2[rr].x, bj2[cc].x, acc[rr][cc]));
    }

    const int GRB = jb + 64 + RB, GCB = jb + 64 + CB;
#pragma unroll
    for (int rr = 0; rr < 8; rr++) {
        int row = rg * 8 + rr;
        if (row < vr) {
#pragma unroll
            for (int cc = 0; cc < 8; cc++) {
                int col = cg + 16 * cc;
                if (col < vc)
                    Cb[(size_t)(GRB + row) * NA + GCB + col] = acc[rr][cc];
            }
        }
    }
}

// ------------------------------------------- K3b: fused tail (j=5,6,7) — round-5 proven
__global__ void __launch_bounds__(256, 1) k_tail(float* __restrict__ C,
                                                 float* __restrict__ r1,
                                                 float* __restrict__ r2) {
    const int b = blockIdx.x;
    float* __restrict__ Cb = C + (size_t)b * NN;
    const int tid = threadIdx.x;
    __shared__ float T[TS * TSTR];
    __shared__ float invd[64], y1s[64], y2s[64];

    for (int f = tid; f < TS * TS; f += 256) {
        int row = f / TS, c = f - row * TS;
        T[row * TSTR + c] = Cb[(size_t)(TB + row) * NA + TB + c];
    }
    __syncthreads();

#pragma unroll 1
    for (int p = 0; p < 3; p++) {
        const int pb = p * 64;
        const int msub = TS - pb - 64;

        if (tid < 64) {
            const int t = tid;
            float cl[64];
#pragma unroll
            for (int i = 0; i < 64; i++)
                cl[i] = (i >= t) ? T[(pb + i) * TSTR + pb + t]
                                 : T[(pb + t) * TSTR + pb + i];
#pragma unroll
            for (int k = 0; k < 64; k++) {
                float pivot = rl(cl[k], k);
                float invp = 1.0f / pivot;
                float factor = (t > k) ? (cl[k] * invp) : 0.0f;
#pragma unroll
                for (int i = k + 1; i < 64; i++) {
                    float bc = rl(cl[i], k);
                    cl[i] -= bc * factor;
                }
            }
            float rs = 1.0f / sqrtf(cl[t]);
            invd[t] = rs;
#pragma unroll
            for (int i = 0; i < 64; i++) {
                float lv = cl[i] * rs;
                if (i >= t) T[(pb + i) * TSTR + pb + t] = lv;   // L (column t)
                if (i > t)  T[(pb + t) * TSTR + pb + i] = lv;   // L^T (row t)
            }
            // fused forward substitution, both RHS
            float v1 = r1[(size_t)b * NA + TB + pb + t];
            float v2 = r2[(size_t)b * NA + TB + pb + t];
#pragma unroll
            for (int k = 0; k < 64; k++) {
                float rsk = rl(rs, k);
                float y1k = rl(v1, k) * rsk;
                float y2k = rl(v2, k) * rsk;
                if (t == k) {
                    y1s[t] = y1k; y2s[t] = y2k;
                    r1[(size_t)b * NA + TB + pb + t] = y1k;
                    r2[(size_t)b * NA + TB + pb + t] = y2k;
                }
                float lv = (t > k) ? T[(pb + t) * TSTR + pb + k] : 0.f;
                v1 -= lv * y1k;
                v2 -= lv * y2k;
            }
        }
        __syncthreads();

        if (msub > 0) {
            if (tid < msub) {
                const int row_l = pb + 64 + tid;
                float rv[64];
#pragma unroll
                for (int k = 0; k < 64; k++) rv[k] = T[row_l * TSTR + pb + k];
#pragma unroll
                for (int k = 0; k < 64; k++) {
                    float yk = rv[k] * invd[k];
                    rv[k] = yk;
                    const float* LTrow = &T[(pb + k) * TSTR + pb];
#pragma unroll
                    for (int i = k + 1; i < 64; i++)
                        rv[i] -= LTrow[i] * yk;
                }
#pragma unroll
                for (int k = 0; k < 64; k++) T[row_l * TSTR + pb + k] = rv[k];
                float a1 = 0.f, a2 = 0.f;
#pragma unroll
                for (int k = 0; k < 64; k++) {
                    a1 = fmaf(rv[k], y1s[k], a1);
                    a2 = fmaf(rv[k], y2s[k], a2);
                }
                r1[(size_t)b * NA + TB + row_l] -= a1;
                r2[(size_t)b * NA + TB + row_l] -= a2;
            }
            __syncthreads();

            const int rbase = pb + 64;
            if (p == 0) {
                // 128x128 trailing, 8x8 per thread
                const int rg = tid >> 4, cg = tid & 15;
                float acc[8][8];
#pragma unroll
                for (int rr = 0; rr < 8; rr++)
#pragma unroll
                    for (int cc = 0; cc < 8; cc++)
                        acc[rr][cc] = T[(rbase + rg * 8 + rr) * TSTR + rbase + cg * 8 + cc];
#pragma unroll 4
                for (int k = 0; k < 64; k++) {
                    float ai[8], bj[8];
#pragma unroll
                    for (int rr = 0; rr < 8; rr++)
                        ai[rr] = T[(rbase + rg * 8 + rr) * TSTR + pb + k];
#pragma unroll
                    for (int cc = 0; cc < 8; cc++)
                        bj[cc] = T[(rbase + cg * 8 + cc) * TSTR + pb + k];
#pragma unroll
                    for (int rr = 0; rr < 8; rr++)
#pragma unroll
                        for (int cc = 0; cc < 8; cc++)
                            acc[rr][cc] = fmaf(-ai[rr], bj[cc], acc[rr][cc]);
                }
#pragma unroll
                for (int rr = 0; rr < 8; rr++)
#pragma unroll
                    for (int cc = 0; cc < 8; cc++)
                        T[(rbase + rg * 8 + rr) * TSTR + rbase + cg * 8 + cc] = acc[rr][cc];
            } else {
                // 64x64 trailing, 4x4 per thread
                const int rg = tid >> 4, cg = tid & 15;
                float acc[4][4];
#pragma unroll
                for (int rr = 0; rr < 4; rr++)
#pragma unroll
                    for (int cc = 0; cc < 4; cc++)
                        acc[rr][cc] = T[(rbase + rg * 4 + rr) * TSTR + rbase + cg * 4 + cc];
#pragma unroll 4
                for (int k = 0; k < 64; k++) {
                    float ai[4], bj[4];
#pragma unroll
                    for (int rr = 0; rr < 4; rr++)
                        ai[rr] = T[(rbase + rg * 4 + rr) * TSTR + pb + k];
#pragma unroll
                    for (int cc = 0; cc < 4; cc++)
                        bj[cc] = T[(rbase + cg * 4 + cc) * TSTR + pb + k];
#pragma unroll
                    for (int rr = 0; rr < 4; rr++)
#pragma unroll
                        for (int cc = 0; cc < 4; cc++)
                            acc[rr][cc] = fmaf(-ai[rr], bj[cc], acc[rr][cc]);
                }
#pragma unroll
                for (int rr = 0; rr < 4; rr++)
#pragma unroll
                    for (int cc = 0; cc < 4; cc++)
                        T[(rbase + rg * 4 + rr) * TSTR + rbase + cg * 4 + cc] = acc[rr][cc];
            }
        }
        __syncthreads();
    }

    for (int f = tid; f < TS * TS; f += 256) {
        int row = f / TS, c = f - row * TS;
        Cb[(size_t)(TB + row) * NA + TB + c] = T[row * TSTR + c];
    }
}

// ------------------------------------------- K4: backward-only solve (grid = B x 2)
__global__ void __launch_bounds__(512, 1) k_back(const float* __restrict__ C,
                                                 float* __restrict__ r1g,
                                                 float* __restrict__ r2g) {
    const int b = blockIdx.x;
    const int rhs = blockIdx.y;
    const float* Cb = C + (size_t)b * NN;
    const int tid = threadIdx.x;
    __shared__ float D[64 * 65];
    __shared__ float r[NA];
    __shared__ float pb[4][NA];

    float* rg = rhs ? r2g : r1g;
    r[tid] = rg[(size_t)b * NA + tid];

    const int ii = tid & 127;
    const int gg = tid >> 7;
    for (int j = 7; j >= 0; j--) {
        const int jb = j * 64;
        __syncthreads();
#pragma unroll
        for (int e = 0; e < 8; e++) {
            int f = e * 512 + tid;
            int row = f >> 6, cc = f & 63;
            D[row * 65 + cc] = Cb[(size_t)(jb + row) * NA + jb + cc];
        }
        __syncthreads();
        if (tid < 64) {
            float val = r[jb + tid];
            float idg = 1.0f / D[tid * 65 + tid];
#pragma unroll
            for (int k = 63; k >= 0; k--) {
                float xk = rl(val, k) * rl(idg, k);
                if (tid == k) r[jb + k] = xk;
                float lv = (tid < k) ? D[k * 65 + tid] : 0.f;
                val -= lv * xk;
            }
        }
        __syncthreads();
        if (jb > 0) {
            const int nf4 = jb >> 2;
            float4 s1 = make_float4(0.f, 0.f, 0.f, 0.f);
            if (ii < nf4) {
#pragma unroll
                for (int gq = 0; gq < 16; gq++) {
                    int g = jb + gg * 16 + gq;
                    float x1 = r[g];
                    float4 Lv = *(const float4*)(Cb + (size_t)g * NA + ii * 4);
                    s1.x += Lv.x * x1; s1.y += Lv.y * x1; s1.z += Lv.z * x1; s1.w += Lv.w * x1;
                }
            }
            *(float4*)(&pb[gg][ii * 4]) = s1;
            __syncthreads();
            if (tid < jb)
                r[tid] -= pb[0][tid] + pb[1][tid] + pb[2][tid] + pb[3][tid];
        }
    }
    __syncthreads();

    rg[(size_t)b * NA + tid] = r[tid];
}

// ------------------------------------------- K5: mu, q, energy from x1, x2
__global__ void __launch_bounds__(512, 1) k_final(const float* __restrict__ x1,
                                                  const float* __restrict__ x2,
                                                  const float* __restrict__ chiA,
                                                  const float* __restrict__ Qtot,
                                                  float* __restrict__ out, int B) {
    const int b = blockIdx.x;
    const int tid = threadIdx.x;
    __shared__ float red[16];
    __shared__ float muS;

    float v1 = x1[(size_t)b * NA + tid];
    float v2 = x2[(size_t)b * NA + tid];

    float s1p = v1, s2p = v2;
#pragma unroll
    for (int off = 1; off < 64; off <<= 1) {
        s1p += __shfl_xor(s1p, off);
        s2p += __shfl_xor(s2p, off);
    }
    if ((tid & 63) == 0) { red[tid >> 6] = s1p; red[8 + (tid >> 6)] = s2p; }
    __syncthreads();
    if (tid == 0) {
        float s1 = 0.f, s2 = 0.f;
#pragma unroll
        for (int wv = 0; wv < 8; wv++) { s1 += red[wv]; s2 += red[8 + wv]; }
        muS = -(Qtot[b] + s1) / s2;
    }
    __syncthreads();
    float mu = muS;
    float qv = -v1 - mu * v2;
    out[B + (size_t)b * NA + tid] = qv;

    float eacc = chiA[b * NA + tid] * qv;
#pragma unroll
    for (int off = 1; off < 64; off <<= 1) eacc += __shfl_xor(eacc, off);
    __syncthreads();
    if ((tid & 63) == 0) red[tid >> 6] = eacc;
    __syncthreads();
    if (tid == 0) {
        float e = 0.f;
#pragma unroll
        for (int wv = 0; wv < 8; wv++) e += red[wv];
        out[b] = 0.5f * e - 0.5f * mu * Qtot[b];
    }
}

// ---------------------------------------------------------------- host launch
extern "C" void kernel_launch(void* const* d_in, const int* in_sizes, int n_in,
                              void* d_out, int out_size, void* d_ws, size_t ws_size,
                              hipStream_t stream) {
    const int B = in_sizes[3];          // 128 molecules
    const int N = in_sizes[2];          // 65536 atoms
    const float* feats = (const float*)d_in[0];
    const float* pos   = (const float*)d_in[1];
    const int*   type  = (const int*)d_in[2];
    const float* Qt    = (const float*)d_in[3];
    const float* w     = (const float*)d_in[4];
    const float* hard  = (const float*)d_in[5];
    const float* sig   = (const float*)d_in[6];
    float* out = (float*)d_out;
    float* ws  = (float*)d_ws;

    float* C    = ws;                       // B * 512 * 512
    float* chi  = ws + (size_t)B * NN;      // N
    float* diag = chi + N;                  // N
    float* sigA = diag + N;                 // N
    float* r1   = sigA + N;                 // N (rhs1: chi -> y -> x1)
    float* r2   = r1 + N;                   // N (rhs2: 1   -> y -> x2)

    k_pre<<<(N + 255) / 256, 256, 0, stream>>>(feats, w, type, hard, sig,
                                               chi, diag, sigA, r1, r2, N);

    static const int tilesJ[5] = {10, 6, 6, 3, 3};
    for (int j = 0; j < 5; j++) {
        k_panel<<<dim3(2, B), 256, 0, stream>>>(pos, sigA, diag, C, r1, r2, j);
        if (j == 0)
            k_trail<true><<<dim3(tilesJ[j], B), 256, 0, stream>>>(C, pos, sigA, diag, j);
        else
            k_trail<false><<<dim3(tilesJ[j], B), 256, 0, stream>>>(C, pos, sigA, diag, j);
    }
    k_tail<<<B, 256, 0, stream>>>(C, r1, r2);
    k_back<<<dim3(B, 2), 512, 0, stream>>>(C, r1, r2);
    k_final<<<B, 512, 0, stream>>>(r1, r2, chi, Qt, out, B);
}

// Round 12
// 727.432 us; speedup vs baseline: 1.1080x; 1.0005x over previous
//
#include <hip/hip_runtime.h>
#include <math.h>

#define NA 512
#define NN (NA*NA)
#define COULOMB 14.399645478425668f
#define SQRT_PI 1.7724538509055160273f

// tail-fusion region: last 192 rows/cols handled by k_tail in LDS
#define TB 320
#define TS 192
#define TSTR 193

typedef float v2f __attribute__((ext_vector_type(2)));

__device__ __forceinline__ float rl(float x, int lane) {
    return __int_as_float(__builtin_amdgcn_readlane(__float_as_int(x), lane));
}

__device__ __forceinline__ float pair_val(float dx, float dy, float dz,
                                          float s2i, float s2k) {
    float d2 = dx*dx + dy*dy + dz*dz;
    float rinv = rsqrtf(d2);
    return COULOMB * erff(d2 * rinv * rsqrtf(2.f * (s2i + s2k))) * rinv;
}

// ---------------------------------------------------------------- K1: per-atom
// Also initializes the two RHS vectors: r1 = chi, r2 = 1.
__global__ void k_pre(const float* __restrict__ feats, const float* __restrict__ w,
                      const int* __restrict__ type, const float* __restrict__ hard,
                      const float* __restrict__ sigma,
                      float* __restrict__ chi, float* __restrict__ diag,
                      float* __restrict__ sigA,
                      float* __restrict__ r1, float* __restrict__ r2, int N) {
    __shared__ float wl[64];
    int tid = threadIdx.x;
    if (tid < 64) wl[tid] = w[tid];
    __syncthreads();
    int i = blockIdx.x * 256 + tid;
    if (i >= N) return;
    const float4* fp = (const float4*)(feats + (size_t)i * 64);
    float acc = 0.f;
#pragma unroll
    for (int q = 0; q < 16; q++) {
        float4 v = fp[q];
        acc += v.x * wl[4*q] + v.y * wl[4*q+1] + v.z * wl[4*q+2] + v.w * wl[4*q+3];
    }
    chi[i] = acc;
    r1[i] = acc;
    r2[i] = 1.0f;
    int t = type[i];
    float s = sigma[t];
    float h = hard[t];
    sigA[i] = s;
    diag[i] = h * h + COULOMB / (SQRT_PI * s);
}

// ------------------------------------------- K2: diag factor + split panel trsm (j<=4)
// Forward substitution for BOTH RHS fused here (round-11 proven).
__global__ void __launch_bounds__(256, 1) k_panel(const float* __restrict__ pos,
                                                  const float* __restrict__ sigA,
                                                  const float* __restrict__ diagA,
                                                  float* __restrict__ C,
                                                  float* __restrict__ r1,
                                                  float* __restrict__ r2, const int j) {
    const int q = blockIdx.x;
    const int b = blockIdx.y;
    float* __restrict__ Cb = C + (size_t)b * NN;
    const int jb = j * 64;
    const int m = NA - jb - 64;
    const int tid = threadIdx.x;
    __shared__ float D[64 * 65];
    __shared__ float DT[64 * 64];
    __shared__ float invd[64];
    __shared__ float y1s[64], y2s[64];
    __shared__ float px[NA], py[NA], pz[NA], s2s[NA];

    if (j == 0) {
#pragma unroll
        for (int e = 0; e < 2; e++) {
            int i = e * 256 + tid;
            px[i] = pos[((size_t)b * NA + i) * 3 + 0];
            py[i] = pos[((size_t)b * NA + i) * 3 + 1];
            pz[i] = pos[((size_t)b * NA + i) * 3 + 2];
            float s = sigA[b * NA + i];
            s2s[i] = s * s;
        }
        __syncthreads();
    }

#pragma unroll
    for (int e = 0; e < 16; e++) {
        int f = e * 256 + tid;
        int rr = f >> 6, cc = f & 63;
        float v;
        if (j == 0) {
            if (rr == cc) v = diagA[b * NA + rr];
            else v = pair_val(px[rr]-px[cc], py[rr]-py[cc], pz[rr]-pz[cc], s2s[rr], s2s[cc]);
        } else {
            v = Cb[(size_t)(jb + rr) * NA + jb + cc];
        }
        D[rr * 65 + cc] = v;
    }

    const int h = m >> 1;
    const int r0 = q ? h : 0;
    const int nr = q ? (m - h) : h;
    const int r = tid - 32;
    const bool hasrow = (r >= 0 && r < nr);
    const int grow = jb + 64 + r0 + r;
    float rv[64];
    if (hasrow) {
        if (j == 0) {
#pragma unroll
            for (int k = 0; k < 64; k++)
                rv[k] = pair_val(px[grow]-px[k], py[grow]-py[k], pz[grow]-pz[k],
                                 s2s[grow], s2s[k]);
        } else {
            const float4* rp = (const float4*)(Cb + (size_t)grow * NA + jb);
#pragma unroll
            for (int qq = 0; qq < 16; qq++) {
                float4 v = rp[qq];
                rv[4*qq] = v.x; rv[4*qq+1] = v.y; rv[4*qq+2] = v.z; rv[4*qq+3] = v.w;
            }
        }
    }
    __syncthreads();

    if (tid < 64) {
        const int t = tid;
        float cl[64];
#pragma unroll
        for (int i = 0; i < 64; i++) cl[i] = (i >= t) ? D[i * 65 + t] : D[t * 65 + i];
#pragma unroll
        for (int k = 0; k < 64; k++) {
            float pivot = rl(cl[k], k);
            float invp = 1.0f / pivot;
            float factor = (t > k) ? (cl[k] * invp) : 0.0f;
#pragma unroll
            for (int i = k + 1; i < 64; i++) {
                float bc = rl(cl[i], k);
                cl[i] -= bc * factor;
            }
        }
        float rs = 1.0f / sqrtf(cl[t]);
        invd[t] = rs;
#pragma unroll
        for (int i = 0; i < 64; i++)
            if (i >= t) D[i * 65 + t] = cl[i] * rs;

        // ---- fused forward substitution: solve L_jj y = r_j for both RHS.
        float v1 = r1[(size_t)b * NA + jb + t];
        float v2 = r2[(size_t)b * NA + jb + t];
#pragma unroll
        for (int k = 0; k < 64; k++) {
            float rsk = rl(rs, k);
            float y1k = rl(v1, k) * rsk;
            float y2k = rl(v2, k) * rsk;
            if (t == k) {
                y1s[t] = y1k; y2s[t] = y2k;
                if (q == 0) {
                    r1[(size_t)b * NA + jb + t] = y1k;
                    r2[(size_t)b * NA + jb + t] = y2k;
                }
            }
            float lv = (t > k) ? D[t * 65 + k] : 0.f;
            v1 -= lv * y1k;
            v2 -= lv * y2k;
        }
    }
    __syncthreads();

#pragma unroll
    for (int e = 0; e < 16; e++) {
        int f = e * 256 + tid;
        int row = f >> 6, cc = f & 63;
        float v = D[row * 65 + cc];
        DT[row * 64 + cc] = (cc < row) ? v : 0.f;
        if (q == 0 && cc <= row) Cb[(size_t)(jb + row) * NA + jb + cc] = v;
    }
    __syncthreads();

    if (hasrow) {
#pragma unroll
        for (int k = 0; k < 64; k++) {
            float acc = rv[k];
            const float4* Lr = (const float4*)(DT + k * 64);
            const int k4 = k >> 2;
#pragma unroll
            for (int t4 = 0; t4 < k4; t4++) {
                float4 Lv = Lr[t4];
                acc -= Lv.x * rv[4*t4] + Lv.y * rv[4*t4+1] + Lv.z * rv[4*t4+2] + Lv.w * rv[4*t4+3];
            }
#pragma unroll
            for (int tt = k4 * 4; tt < k; tt++) acc -= DT[k * 64 + tt] * rv[tt];
            rv[k] = acc * invd[k];
        }
        float4* rp = (float4*)(Cb + (size_t)grow * NA + jb);
#pragma unroll
        for (int qq = 0; qq < 16; qq++)
            rp[qq] = make_float4(rv[4*qq], rv[4*qq+1], rv[4*qq+2], rv[4*qq+3]);

        // ---- fused forward update: r[grow] -= L_row . y_j (both RHS).
        float a1 = 0.f, a2 = 0.f;
#pragma unroll
        for (int k = 0; k < 64; k++) {
            a1 = fmaf(rv[k], y1s[k], a1);
            a2 = fmaf(rv[k], y2s[k], a2);
        }
        r1[(size_t)b * NA + grow] -= a1;
        r2[(size_t)b * NA + grow] -= a2;
    }
}

// ------------------------------------------- K3: trailing update (j<=4)
// Round-13 proven: LDS stride 66 (8B-aligned even stride), ds_read_b64 for ai/bj,
// dual partial sums per output (.x even-k, .y odd-k).
template<bool GEN>
__global__ void __launch_bounds__(256, 2) k_trail(float* __restrict__ C,
                                                  const float* __restrict__ pos,
                                                  const float* __restrict__ sigA,
                                                  const float* __restrict__ diagA,
                                                  const int j) {
    const int b = blockIdx.y;
    float* __restrict__ Cb = C + (size_t)b * NN;
    const int jb = j * 64;
    const int m = NA - jb - 64;
    int t = blockIdx.x;
    int RI = 0;
    while (t >= RI + 1) { t -= RI + 1; RI++; }
    const int RJ = t;
    const int RB = RI * 128, CB = RJ * 128;
    const int vr = min(128, m - RB);
    const int vc = min(128, m - CB);
    const int tid = threadIdx.x;
    const int rg = tid >> 4, cg = tid & 15;

    __shared__ float As[128 * 66];
    __shared__ float Bs[128 * 66];

    v2f ac2[8][8];

    if (GEN) {
        __shared__ float pAx[128], pAy[128], pAz[128], sA[128], dA[128];
        __shared__ float pBx[128], pBy[128], pBz[128], sB[128];
        if (tid < 128) {
            if (RB + tid < m) {
                int ga = b * NA + jb + 64 + RB + tid;
                pAx[tid] = pos[(size_t)ga * 3 + 0];
                pAy[tid] = pos[(size_t)ga * 3 + 1];
                pAz[tid] = pos[(size_t)ga * 3 + 2];
                float s = sigA[ga]; sA[tid] = s * s;
                dA[tid] = diagA[ga];
            }
        } else {
            int u = tid - 128;
            if (CB + u < m) {
                int gb = b * NA + jb + 64 + CB + u;
                pBx[u] = pos[(size_t)gb * 3 + 0];
                pBy[u] = pos[(size_t)gb * 3 + 1];
                pBz[u] = pos[(size_t)gb * 3 + 2];
                float s = sigA[gb]; sB[u] = s * s;
            }
        }
        __syncthreads();
#pragma unroll
        for (int rr = 0; rr < 8; rr++) {
            int row = rg * 8 + rr;
#pragma unroll
            for (int cc = 0; cc < 8; cc++) {
                int col = cg + 16 * cc;
                float iv;
                if (RB + row == CB + col)
                    iv = dA[row];
                else
                    iv = pair_val(pAx[row]-pBx[col], pAy[row]-pBy[col],
                                  pAz[row]-pBz[col], sA[row], sB[col]);
                ac2[rr][cc].x = iv;
                ac2[rr][cc].y = 0.f;
            }
        }
        __syncthreads();
    } else {
        const int GRB = jb + 64 + RB, GCB = jb + 64 + CB;
#pragma unroll
        for (int rr = 0; rr < 8; rr++) {
            int row = rg * 8 + rr;
#pragma unroll
            for (int cc = 0; cc < 8; cc++) {
                int col = cg + 16 * cc;
                ac2[rr][cc].x = (row < vr && col < vc)
                    ? Cb[(size_t)(GRB + row) * NA + GCB + col] : 0.f;
                ac2[rr][cc].y = 0.f;
            }
        }
    }

    const float* Pan = Cb + (size_t)(jb + 64) * NA + jb;
#pragma unroll
    for (int e = 0; e < 8; e++) {
        int f = e * 256 + tid;
        int row = f >> 4, s = f & 15;
        float4 v = make_float4(0.f, 0.f, 0.f, 0.f);
        if (row < vr) v = *(const float4*)(Pan + (size_t)(RB + row) * NA + s * 4);
        As[row * 66 + s * 4 + 0] = v.x;
        As[row * 66 + s * 4 + 1] = v.y;
        As[row * 66 + s * 4 + 2] = v.z;
        As[row * 66 + s * 4 + 3] = v.w;
        float4 u = make_float4(0.f, 0.f, 0.f, 0.f);
        if (row < vc) u = *(const float4*)(Pan + (size_t)(CB + row) * NA + s * 4);
        Bs[row * 66 + s * 4 + 0] = u.x;
        Bs[row * 66 + s * 4 + 1] = u.y;
        Bs[row * 66 + s * 4 + 2] = u.z;
        Bs[row * 66 + s * 4 + 3] = u.w;
    }
    __syncthreads();

#pragma unroll 2
    for (int k = 0; k < 64; k += 2) {
        v2f ai2[8], bj2[8];
#pragma unroll
        for (int rr = 0; rr < 8; rr++)
            ai2[rr] = *(const v2f*)&As[(rg * 8 + rr) * 66 + k];
#pragma unroll
        for (int cc = 0; cc < 8; cc++)
            bj2[cc] = *(const v2f*)&Bs[(cg + 16 * cc) * 66 + k];
#pragma unroll
        for (int rr = 0; rr < 8; rr++)
#pragma unroll
            for (int cc = 0; cc < 8; cc++) {
                ac2[rr][cc].x = fmaf(-ai2[rr].x, bj2[cc].x, ac2[rr][cc].x);
                ac2[rr][cc].y = fmaf(-ai2[rr].y, bj2[cc].y, ac2[rr][cc].y);
            }
    }

    const int GRB = jb + 64 + RB, GCB = jb + 64 + CB;
#pragma unroll
    for (int rr = 0; rr < 8; rr++) {
        int row = rg * 8 + rr;
        if (row < vr) {
#pragma unroll
            for (int cc = 0; cc < 8; cc++) {
                int col = cg + 16 * cc;
                if (col < vc)
                    Cb[(size_t)(GRB + row) * NA + GCB + col] = ac2[rr][cc].x + ac2[rr][cc].y;
            }
        }
    }
}

// ------------------------------------------- K3b: fused tail (j=5,6,7) — round-5 proven
__global__ void __launch_bounds__(256, 1) k_tail(float* __restrict__ C,
                                                 float* __restrict__ r1,
                                                 float* __restrict__ r2) {
    const int b = blockIdx.x;
    float* __restrict__ Cb = C + (size_t)b * NN;
    const int tid = threadIdx.x;
    __shared__ float T[TS * TSTR];
    __shared__ float invd[64], y1s[64], y2s[64];

    for (int f = tid; f < TS * TS; f += 256) {
        int row = f / TS, c = f - row * TS;
        T[row * TSTR + c] = Cb[(size_t)(TB + row) * NA + TB + c];
    }
    __syncthreads();

#pragma unroll 1
    for (int p = 0; p < 3; p++) {
        const int pb = p * 64;
        const int msub = TS - pb - 64;

        if (tid < 64) {
            const int t = tid;
            float cl[64];
#pragma unroll
            for (int i = 0; i < 64; i++)
                cl[i] = (i >= t) ? T[(pb + i) * TSTR + pb + t]
                                 : T[(pb + t) * TSTR + pb + i];
#pragma unroll
            for (int k = 0; k < 64; k++) {
                float pivot = rl(cl[k], k);
                float invp = 1.0f / pivot;
                float factor = (t > k) ? (cl[k] * invp) : 0.0f;
#pragma unroll
                for (int i = k + 1; i < 64; i++) {
                    float bc = rl(cl[i], k);
                    cl[i] -= bc * factor;
                }
            }
            float rs = 1.0f / sqrtf(cl[t]);
            invd[t] = rs;
#pragma unroll
            for (int i = 0; i < 64; i++) {
                float lv = cl[i] * rs;
                if (i >= t) T[(pb + i) * TSTR + pb + t] = lv;   // L (column t)
                if (i > t)  T[(pb + t) * TSTR + pb + i] = lv;   // L^T (row t)
            }
            // fused forward substitution, both RHS
            float v1 = r1[(size_t)b * NA + TB + pb + t];
            float v2 = r2[(size_t)b * NA + TB + pb + t];
#pragma unroll
            for (int k = 0; k < 64; k++) {
                float rsk = rl(rs, k);
                float y1k = rl(v1, k) * rsk;
                float y2k = rl(v2, k) * rsk;
                if (t == k) {
                    y1s[t] = y1k; y2s[t] = y2k;
                    r1[(size_t)b * NA + TB + pb + t] = y1k;
                    r2[(size_t)b * NA + TB + pb + t] = y2k;
                }
                float lv = (t > k) ? T[(pb + t) * TSTR + pb + k] : 0.f;
                v1 -= lv * y1k;
                v2 -= lv * y2k;
            }
        }
        __syncthreads();

        if (msub > 0) {
            if (tid < msub) {
                const int row_l = pb + 64 + tid;
                float rv[64];
#pragma unroll
                for (int k = 0; k < 64; k++) rv[k] = T[row_l * TSTR + pb + k];
#pragma unroll
                for (int k = 0; k < 64; k++) {
                    float yk = rv[k] * invd[k];
                    rv[k] = yk;
                    const float* LTrow = &T[(pb + k) * TSTR + pb];
#pragma unroll
                    for (int i = k + 1; i < 64; i++)
                        rv[i] -= LTrow[i] * yk;
                }
#pragma unroll
                for (int k = 0; k < 64; k++) T[row_l * TSTR + pb + k] = rv[k];
                float a1 = 0.f, a2 = 0.f;
#pragma unroll
                for (int k = 0; k < 64; k++) {
                    a1 = fmaf(rv[k], y1s[k], a1);
                    a2 = fmaf(rv[k], y2s[k], a2);
                }
                r1[(size_t)b * NA + TB + row_l] -= a1;
                r2[(size_t)b * NA + TB + row_l] -= a2;
            }
            __syncthreads();

            const int rbase = pb + 64;
            if (p == 0) {
                // 128x128 trailing, 8x8 per thread
                const int rg = tid >> 4, cg = tid & 15;
                float acc[8][8];
#pragma unroll
                for (int rr = 0; rr < 8; rr++)
#pragma unroll
                    for (int cc = 0; cc < 8; cc++)
                        acc[rr][cc] = T[(rbase + rg * 8 + rr) * TSTR + rbase + cg * 8 + cc];
#pragma unroll 4
                for (int k = 0; k < 64; k++) {
                    float ai[8], bj[8];
#pragma unroll
                    for (int rr = 0; rr < 8; rr++)
                        ai[rr] = T[(rbase + rg * 8 + rr) * TSTR + pb + k];
#pragma unroll
                    for (int cc = 0; cc < 8; cc++)
                        bj[cc] = T[(rbase + cg * 8 + cc) * TSTR + pb + k];
#pragma unroll
                    for (int rr = 0; rr < 8; rr++)
#pragma unroll
                        for (int cc = 0; cc < 8; cc++)
                            acc[rr][cc] = fmaf(-ai[rr], bj[cc], acc[rr][cc]);
                }
#pragma unroll
                for (int rr = 0; rr < 8; rr++)
#pragma unroll
                    for (int cc = 0; cc < 8; cc++)
                        T[(rbase + rg * 8 + rr) * TSTR + rbase + cg * 8 + cc] = acc[rr][cc];
            } else {
                // 64x64 trailing, 4x4 per thread
                const int rg = tid >> 4, cg = tid & 15;
                float acc[4][4];
#pragma unroll
                for (int rr = 0; rr < 4; rr++)
#pragma unroll
                    for (int cc = 0; cc < 4; cc++)
                        acc[rr][cc] = T[(rbase + rg * 4 + rr) * TSTR + rbase + cg * 4 + cc];
#pragma unroll 4
                for (int k = 0; k < 64; k++) {
                    float ai[4], bj[4];
#pragma unroll
                    for (int rr = 0; rr < 4; rr++)
                        ai[rr] = T[(rbase + rg * 4 + rr) * TSTR + pb + k];
#pragma unroll
                    for (int cc = 0; cc < 4; cc++)
                        bj[cc] = T[(rbase + cg * 4 + cc) * TSTR + pb + k];
#pragma unroll
                    for (int rr = 0; rr < 4; rr++)
#pragma unroll
                        for (int cc = 0; cc < 4; cc++)
                            acc[rr][cc] = fmaf(-ai[rr], bj[cc], acc[rr][cc]);
                }
#pragma unroll
                for (int rr = 0; rr < 4; rr++)
#pragma unroll
                    for (int cc = 0; cc < 4; cc++)
                        T[(rbase + rg * 4 + rr) * TSTR + rbase + cg * 4 + cc] = acc[rr][cc];
            }
        }
        __syncthreads();
    }

    for (int f = tid; f < TS * TS; f += 256) {
        int row = f / TS, c = f - row * TS;
        Cb[(size_t)(TB + row) * NA + TB + c] = T[row * TSTR + c];
    }
}

// ------------------------------------------- K4: backward-only solve (grid = B x 2)
__global__ void __launch_bounds__(512, 1) k_back(const float* __restrict__ C,
                                                 float* __restrict__ r1g,
                                                 float* __restrict__ r2g) {
    const int b = blockIdx.x;
    const int rhs = blockIdx.y;
    const float* Cb = C + (size_t)b * NN;
    const int tid = threadIdx.x;
    __shared__ float D[64 * 65];
    __shared__ float r[NA];
    __shared__ float pb[4][NA];

    float* rg = rhs ? r2g : r1g;
    r[tid] = rg[(size_t)b * NA + tid];

    const int ii = tid & 127;
    const int gg = tid >> 7;
    for (int j = 7; j >= 0; j--) {
        const int jb = j * 64;
        __syncthreads();
#pragma unroll
        for (int e = 0; e < 8; e++) {
            int f = e * 512 + tid;
            int row = f >> 6, cc = f & 63;
            D[row * 65 + cc] = Cb[(size_t)(jb + row) * NA + jb + cc];
        }
        __syncthreads();
        if (tid < 64) {
            float val = r[jb + tid];
            float idg = 1.0f / D[tid * 65 + tid];
#pragma unroll
            for (int k = 63; k >= 0; k--) {
                float xk = rl(val, k) * rl(idg, k);
                if (tid == k) r[jb + k] = xk;
                float lv = (tid < k) ? D[k * 65 + tid] : 0.f;
                val -= lv * xk;
            }
        }
        __syncthreads();
        if (jb > 0) {
            const int nf4 = jb >> 2;
            float4 s1 = make_float4(0.f, 0.f, 0.f, 0.f);
            if (ii < nf4) {
#pragma unroll
                for (int gq = 0; gq < 16; gq++) {
                    int g = jb + gg * 16 + gq;
                    float x1 = r[g];
                    float4 Lv = *(const float4*)(Cb + (size_t)g * NA + ii * 4);
                    s1.x += Lv.x * x1; s1.y += Lv.y * x1; s1.z += Lv.z * x1; s1.w += Lv.w * x1;
                }
            }
            *(float4*)(&pb[gg][ii * 4]) = s1;
            __syncthreads();
            if (tid < jb)
                r[tid] -= pb[0][tid] + pb[1][tid] + pb[2][tid] + pb[3][tid];
        }
    }
    __syncthreads();

    rg[(size_t)b * NA + tid] = r[tid];
}

// ------------------------------------------- K5: mu, q, energy from x1, x2
__global__ void __launch_bounds__(512, 1) k_final(const float* __restrict__ x1,
                                                  const float* __restrict__ x2,
                                                  const float* __restrict__ chiA,
                                                  const float* __restrict__ Qtot,
                                                  float* __restrict__ out, int B) {
    const int b = blockIdx.x;
    const int tid = threadIdx.x;
    __shared__ float red[16];
    __shared__ float muS;

    float v1 = x1[(size_t)b * NA + tid];
    float v2 = x2[(size_t)b * NA + tid];

    float s1p = v1, s2p = v2;
#pragma unroll
    for (int off = 1; off < 64; off <<= 1) {
        s1p += __shfl_xor(s1p, off);
        s2p += __shfl_xor(s2p, off);
    }
    if ((tid & 63) == 0) { red[tid >> 6] = s1p; red[8 + (tid >> 6)] = s2p; }
    __syncthreads();
    if (tid == 0) {
        float s1 = 0.f, s2 = 0.f;
#pragma unroll
        for (int wv = 0; wv < 8; wv++) { s1 += red[wv]; s2 += red[8 + wv]; }
        muS = -(Qtot[b] + s1) / s2;
    }
    __syncthreads();
    float mu = muS;
    float qv = -v1 - mu * v2;
    out[B + (size_t)b * NA + tid] = qv;

    float eacc = chiA[b * NA + tid] * qv;
#pragma unroll
    for (int off = 1; off < 64; off <<= 1) eacc += __shfl_xor(eacc, off);
    __syncthreads();
    if ((tid & 63) == 0) red[tid >> 6] = eacc;
    __syncthreads();
    if (tid == 0) {
        float e = 0.f;
#pragma unroll
        for (int wv = 0; wv < 8; wv++) e += red[wv];
        out[b] = 0.5f * e - 0.5f * mu * Qtot[b];
    }
}

// ---------------------------------------------------------------- host launch
extern "C" void kernel_launch(void* const* d_in, const int* in_sizes, int n_in,
                              void* d_out, int out_size, void* d_ws, size_t ws_size,
                              hipStream_t stream) {
    const int B = in_sizes[3];          // 128 molecules
    const int N = in_sizes[2];          // 65536 atoms
    const float* feats = (const float*)d_in[0];
    const float* pos   = (const float*)d_in[1];
    const int*   type  = (const int*)d_in[2];
    const float* Qt    = (const float*)d_in[3];
    const float* w     = (const float*)d_in[4];
    const float* hard  = (const float*)d_in[5];
    const float* sig   = (const float*)d_in[6];
    float* out = (float*)d_out;
    float* ws  = (float*)d_ws;

    float* C    = ws;                       // B * 512 * 512
    float* chi  = ws + (size_t)B * NN;      // N
    float* diag = chi + N;                  // N
    float* sigA = diag + N;                 // N
    float* r1   = sigA + N;                 // N (rhs1: chi -> y -> x1)
    float* r2   = r1 + N;                   // N (rhs2: 1   -> y -> x2)

    k_pre<<<(N + 255) / 256, 256, 0, stream>>>(feats, w, type, hard, sig,
                                               chi, diag, sigA, r1, r2, N);

    static const int tilesJ[5] = {10, 6, 6, 3, 3};
    for (int j = 0; j < 5; j++) {
        k_panel<<<dim3(2, B), 256, 0, stream>>>(pos, sigA, diag, C, r1, r2, j);
        if (j == 0)
            k_trail<true><<<dim3(tilesJ[j], B), 256, 0, stream>>>(C, pos, sigA, diag, j);
        else
            k_trail<false><<<dim3(tilesJ[j], B), 256, 0, stream>>>(C, pos, sigA, diag, j);
    }
    k_tail<<<B, 256, 0, stream>>>(C, r1, r2);
    k_back<<<dim3(B, 2), 512, 0, stream>>>(C, r1, r2);
    k_final<<<B, 512, 0, stream>>>(r1, r2, chi, Qt, out, B);
}

// Round 13
// 719.412 us; speedup vs baseline: 1.1204x; 1.0111x over previous
//
#include <hip/hip_runtime.h>
#include <math.h>

#define NA 512
#define NN (NA*NA)
#define COULOMB 14.399645478425668f
#define SQRT_PI 1.7724538509055160273f

// tail-fusion region: last 192 rows/cols handled by k_tail in LDS
#define TB 320
#define TS 192
#define TSTR 193

typedef float v2f __attribute__((ext_vector_type(2)));

__device__ __forceinline__ float rl(float x, int lane) {
    return __int_as_float(__builtin_amdgcn_readlane(__float_as_int(x), lane));
}

__device__ __forceinline__ float pair_val(float dx, float dy, float dz,
                                          float s2i, float s2k) {
    float d2 = dx*dx + dy*dy + dz*dz;
    float rinv = rsqrtf(d2);
    return COULOMB * erff(d2 * rinv * rsqrtf(2.f * (s2i + s2k))) * rinv;
}

// ---------------------------------------------------------------- K1: per-atom
// Also initializes the two RHS vectors: r1 = chi, r2 = 1.
__global__ void k_pre(const float* __restrict__ feats, const float* __restrict__ w,
                      const int* __restrict__ type, const float* __restrict__ hard,
                      const float* __restrict__ sigma,
                      float* __restrict__ chi, float* __restrict__ diag,
                      float* __restrict__ sigA,
                      float* __restrict__ r1, float* __restrict__ r2, int N) {
    __shared__ float wl[64];
    int tid = threadIdx.x;
    if (tid < 64) wl[tid] = w[tid];
    __syncthreads();
    int i = blockIdx.x * 256 + tid;
    if (i >= N) return;
    const float4* fp = (const float4*)(feats + (size_t)i * 64);
    float acc = 0.f;
#pragma unroll
    for (int q = 0; q < 16; q++) {
        float4 v = fp[q];
        acc += v.x * wl[4*q] + v.y * wl[4*q+1] + v.z * wl[4*q+2] + v.w * wl[4*q+3];
    }
    chi[i] = acc;
    r1[i] = acc;
    r2[i] = 1.0f;
    int t = type[i];
    float s = sigma[t];
    float h = hard[t];
    sigA[i] = s;
    diag[i] = h * h + COULOMB / (SQRT_PI * s);
}

// ------------------------------------------- K2: diag factor + split panel trsm (j<=4)
// Forward substitution for BOTH RHS fused here (round-11 proven).
__global__ void __launch_bounds__(256, 1) k_panel(const float* __restrict__ pos,
                                                  const float* __restrict__ sigA,
                                                  const float* __restrict__ diagA,
                                                  float* __restrict__ C,
                                                  float* __restrict__ r1,
                                                  float* __restrict__ r2, const int j) {
    const int q = blockIdx.x;
    const int b = blockIdx.y;
    float* __restrict__ Cb = C + (size_t)b * NN;
    const int jb = j * 64;
    const int m = NA - jb - 64;
    const int tid = threadIdx.x;
    __shared__ float D[64 * 65];
    __shared__ float DT[64 * 64];
    __shared__ float invd[64];
    __shared__ float y1s[64], y2s[64];
    __shared__ float px[NA], py[NA], pz[NA], s2s[NA];

    if (j == 0) {
#pragma unroll
        for (int e = 0; e < 2; e++) {
            int i = e * 256 + tid;
            px[i] = pos[((size_t)b * NA + i) * 3 + 0];
            py[i] = pos[((size_t)b * NA + i) * 3 + 1];
            pz[i] = pos[((size_t)b * NA + i) * 3 + 2];
            float s = sigA[b * NA + i];
            s2s[i] = s * s;
        }
        __syncthreads();
    }

#pragma unroll
    for (int e = 0; e < 16; e++) {
        int f = e * 256 + tid;
        int rr = f >> 6, cc = f & 63;
        float v;
        if (j == 0) {
            if (rr == cc) v = diagA[b * NA + rr];
            else v = pair_val(px[rr]-px[cc], py[rr]-py[cc], pz[rr]-pz[cc], s2s[rr], s2s[cc]);
        } else {
            v = Cb[(size_t)(jb + rr) * NA + jb + cc];
        }
        D[rr * 65 + cc] = v;
    }

    const int h = m >> 1;
    const int r0 = q ? h : 0;
    const int nr = q ? (m - h) : h;
    const int r = tid - 32;
    const bool hasrow = (r >= 0 && r < nr);
    const int grow = jb + 64 + r0 + r;
    float rv[64];
    if (hasrow) {
        if (j == 0) {
#pragma unroll
            for (int k = 0; k < 64; k++)
                rv[k] = pair_val(px[grow]-px[k], py[grow]-py[k], pz[grow]-pz[k],
                                 s2s[grow], s2s[k]);
        } else {
            const float4* rp = (const float4*)(Cb + (size_t)grow * NA + jb);
#pragma unroll
            for (int qq = 0; qq < 16; qq++) {
                float4 v = rp[qq];
                rv[4*qq] = v.x; rv[4*qq+1] = v.y; rv[4*qq+2] = v.z; rv[4*qq+3] = v.w;
            }
        }
    }
    __syncthreads();

    if (tid < 64) {
        const int t = tid;
        float cl[64];
#pragma unroll
        for (int i = 0; i < 64; i++) cl[i] = (i >= t) ? D[i * 65 + t] : D[t * 65 + i];
#pragma unroll
        for (int k = 0; k < 64; k++) {
            float pivot = rl(cl[k], k);
            float invp = 1.0f / pivot;
            float factor = (t > k) ? (cl[k] * invp) : 0.0f;
#pragma unroll
            for (int i = k + 1; i < 64; i++) {
                float bc = rl(cl[i], k);
                cl[i] -= bc * factor;
            }
        }
        float rs = 1.0f / sqrtf(cl[t]);
        invd[t] = rs;
#pragma unroll
        for (int i = 0; i < 64; i++)
            if (i >= t) D[i * 65 + t] = cl[i] * rs;

        // ---- fused forward substitution: solve L_jj y = r_j for both RHS.
        float v1 = r1[(size_t)b * NA + jb + t];
        float v2 = r2[(size_t)b * NA + jb + t];
#pragma unroll
        for (int k = 0; k < 64; k++) {
            float rsk = rl(rs, k);
            float y1k = rl(v1, k) * rsk;
            float y2k = rl(v2, k) * rsk;
            if (t == k) {
                y1s[t] = y1k; y2s[t] = y2k;
                if (q == 0) {
                    r1[(size_t)b * NA + jb + t] = y1k;
                    r2[(size_t)b * NA + jb + t] = y2k;
                }
            }
            float lv = (t > k) ? D[t * 65 + k] : 0.f;
            v1 -= lv * y1k;
            v2 -= lv * y2k;
        }
    }
    __syncthreads();

#pragma unroll
    for (int e = 0; e < 16; e++) {
        int f = e * 256 + tid;
        int row = f >> 6, cc = f & 63;
        float v = D[row * 65 + cc];
        DT[row * 64 + cc] = (cc < row) ? v : 0.f;
        if (q == 0 && cc <= row) Cb[(size_t)(jb + row) * NA + jb + cc] = v;
    }
    __syncthreads();

    if (hasrow) {
#pragma unroll
        for (int k = 0; k < 64; k++) {
            float acc = rv[k];
            const float4* Lr = (const float4*)(DT + k * 64);
            const int k4 = k >> 2;
#pragma unroll
            for (int t4 = 0; t4 < k4; t4++) {
                float4 Lv = Lr[t4];
                acc -= Lv.x * rv[4*t4] + Lv.y * rv[4*t4+1] + Lv.z * rv[4*t4+2] + Lv.w * rv[4*t4+3];
            }
#pragma unroll
            for (int tt = k4 * 4; tt < k; tt++) acc -= DT[k * 64 + tt] * rv[tt];
            rv[k] = acc * invd[k];
        }
        float4* rp = (float4*)(Cb + (size_t)grow * NA + jb);
#pragma unroll
        for (int qq = 0; qq < 16; qq++)
            rp[qq] = make_float4(rv[4*qq], rv[4*qq+1], rv[4*qq+2], rv[4*qq+3]);

        // ---- fused forward update: r[grow] -= L_row . y_j (both RHS).
        float a1 = 0.f, a2 = 0.f;
#pragma unroll
        for (int k = 0; k < 64; k++) {
            a1 = fmaf(rv[k], y1s[k], a1);
            a2 = fmaf(rv[k], y2s[k], a2);
        }
        r1[(size_t)b * NA + grow] -= a1;
        r2[(size_t)b * NA + grow] -= a2;
    }
}

// ------------------------------------------- K3: trailing update (j<=4)
// Round-13 proven: LDS stride 66 (8B-aligned even stride), ds_read_b64 for ai/bj,
// dual partial sums per output (.x even-k, .y odd-k).
template<bool GEN>
__global__ void __launch_bounds__(256, 2) k_trail(float* __restrict__ C,
                                                  const float* __restrict__ pos,
                                                  const float* __restrict__ sigA,
                                                  const float* __restrict__ diagA,
                                                  const int j) {
    const int b = blockIdx.y;
    float* __restrict__ Cb = C + (size_t)b * NN;
    const int jb = j * 64;
    const int m = NA - jb - 64;
    int t = blockIdx.x;
    int RI = 0;
    while (t >= RI + 1) { t -= RI + 1; RI++; }
    const int RJ = t;
    const int RB = RI * 128, CB = RJ * 128;
    const int vr = min(128, m - RB);
    const int vc = min(128, m - CB);
    const int tid = threadIdx.x;
    const int rg = tid >> 4, cg = tid & 15;

    __shared__ float As[128 * 66];
    __shared__ float Bs[128 * 66];

    v2f ac2[8][8];

    if (GEN) {
        __shared__ float pAx[128], pAy[128], pAz[128], sA[128], dA[128];
        __shared__ float pBx[128], pBy[128], pBz[128], sB[128];
        if (tid < 128) {
            if (RB + tid < m) {
                int ga = b * NA + jb + 64 + RB + tid;
                pAx[tid] = pos[(size_t)ga * 3 + 0];
                pAy[tid] = pos[(size_t)ga * 3 + 1];
                pAz[tid] = pos[(size_t)ga * 3 + 2];
                float s = sigA[ga]; sA[tid] = s * s;
                dA[tid] = diagA[ga];
            }
        } else {
            int u = tid - 128;
            if (CB + u < m) {
                int gb = b * NA + jb + 64 + CB + u;
                pBx[u] = pos[(size_t)gb * 3 + 0];
                pBy[u] = pos[(size_t)gb * 3 + 1];
                pBz[u] = pos[(size_t)gb * 3 + 2];
                float s = sigA[gb]; sB[u] = s * s;
            }
        }
        __syncthreads();
#pragma unroll
        for (int rr = 0; rr < 8; rr++) {
            int row = rg * 8 + rr;
#pragma unroll
            for (int cc = 0; cc < 8; cc++) {
                int col = cg + 16 * cc;
                float iv;
                if (RB + row == CB + col)
                    iv = dA[row];
                else
                    iv = pair_val(pAx[row]-pBx[col], pAy[row]-pBy[col],
                                  pAz[row]-pBz[col], sA[row], sB[col]);
                ac2[rr][cc].x = iv;
                ac2[rr][cc].y = 0.f;
            }
        }
        __syncthreads();
    } else {
        const int GRB = jb + 64 + RB, GCB = jb + 64 + CB;
#pragma unroll
        for (int rr = 0; rr < 8; rr++) {
            int row = rg * 8 + rr;
#pragma unroll
            for (int cc = 0; cc < 8; cc++) {
                int col = cg + 16 * cc;
                ac2[rr][cc].x = (row < vr && col < vc)
                    ? Cb[(size_t)(GRB + row) * NA + GCB + col] : 0.f;
                ac2[rr][cc].y = 0.f;
            }
        }
    }

    const float* Pan = Cb + (size_t)(jb + 64) * NA + jb;
#pragma unroll
    for (int e = 0; e < 8; e++) {
        int f = e * 256 + tid;
        int row = f >> 4, s = f & 15;
        float4 v = make_float4(0.f, 0.f, 0.f, 0.f);
        if (row < vr) v = *(const float4*)(Pan + (size_t)(RB + row) * NA + s * 4);
        As[row * 66 + s * 4 + 0] = v.x;
        As[row * 66 + s * 4 + 1] = v.y;
        As[row * 66 + s * 4 + 2] = v.z;
        As[row * 66 + s * 4 + 3] = v.w;
        float4 u = make_float4(0.f, 0.f, 0.f, 0.f);
        if (row < vc) u = *(const float4*)(Pan + (size_t)(CB + row) * NA + s * 4);
        Bs[row * 66 + s * 4 + 0] = u.x;
        Bs[row * 66 + s * 4 + 1] = u.y;
        Bs[row * 66 + s * 4 + 2] = u.z;
        Bs[row * 66 + s * 4 + 3] = u.w;
    }
    __syncthreads();

#pragma unroll 2
    for (int k = 0; k < 64; k += 2) {
        v2f ai2[8], bj2[8];
#pragma unroll
        for (int rr = 0; rr < 8; rr++)
            ai2[rr] = *(const v2f*)&As[(rg * 8 + rr) * 66 + k];
#pragma unroll
        for (int cc = 0; cc < 8; cc++)
            bj2[cc] = *(const v2f*)&Bs[(cg + 16 * cc) * 66 + k];
#pragma unroll
        for (int rr = 0; rr < 8; rr++)
#pragma unroll
            for (int cc = 0; cc < 8; cc++) {
                ac2[rr][cc].x = fmaf(-ai2[rr].x, bj2[cc].x, ac2[rr][cc].x);
                ac2[rr][cc].y = fmaf(-ai2[rr].y, bj2[cc].y, ac2[rr][cc].y);
            }
    }

    const int GRB = jb + 64 + RB, GCB = jb + 64 + CB;
#pragma unroll
    for (int rr = 0; rr < 8; rr++) {
        int row = rg * 8 + rr;
        if (row < vr) {
#pragma unroll
            for (int cc = 0; cc < 8; cc++) {
                int col = cg + 16 * cc;
                if (col < vc)
                    Cb[(size_t)(GRB + row) * NA + GCB + col] = ac2[rr][cc].x + ac2[rr][cc].y;
            }
        }
    }
}

// ------------------------------------------- K3b: fused tail (j=5,6,7)
// Round-21: 512 threads (was 256). The serial phases (factor tid<64, trsm
// tid<msub<=128) are index-preserved and byte-identical; the thread-parallel
// phases (145KB load/store, syrk) are re-tiled for 512 threads, halving their
// time and doubling resident waves for latency hiding. 1 block/CU unchanged.
__global__ void __launch_bounds__(512, 1) k_tail(float* __restrict__ C,
                                                 float* __restrict__ r1,
                                                 float* __restrict__ r2) {
    const int b = blockIdx.x;
    float* __restrict__ Cb = C + (size_t)b * NN;
    const int tid = threadIdx.x;
    __shared__ float T[TS * TSTR];
    __shared__ float invd[64], y1s[64], y2s[64];

    for (int f = tid; f < TS * TS; f += 512) {
        int row = f / TS, c = f - row * TS;
        T[row * TSTR + c] = Cb[(size_t)(TB + row) * NA + TB + c];
    }
    __syncthreads();

#pragma unroll 1
    for (int p = 0; p < 3; p++) {
        const int pb = p * 64;
        const int msub = TS - pb - 64;

        if (tid < 64) {
            const int t = tid;
            float cl[64];
#pragma unroll
            for (int i = 0; i < 64; i++)
                cl[i] = (i >= t) ? T[(pb + i) * TSTR + pb + t]
                                 : T[(pb + t) * TSTR + pb + i];
#pragma unroll
            for (int k = 0; k < 64; k++) {
                float pivot = rl(cl[k], k);
                float invp = 1.0f / pivot;
                float factor = (t > k) ? (cl[k] * invp) : 0.0f;
#pragma unroll
                for (int i = k + 1; i < 64; i++) {
                    float bc = rl(cl[i], k);
                    cl[i] -= bc * factor;
                }
            }
            float rs = 1.0f / sqrtf(cl[t]);
            invd[t] = rs;
#pragma unroll
            for (int i = 0; i < 64; i++) {
                float lv = cl[i] * rs;
                if (i >= t) T[(pb + i) * TSTR + pb + t] = lv;   // L (column t)
                if (i > t)  T[(pb + t) * TSTR + pb + i] = lv;   // L^T (row t)
            }
            // fused forward substitution, both RHS
            float v1 = r1[(size_t)b * NA + TB + pb + t];
            float v2 = r2[(size_t)b * NA + TB + pb + t];
#pragma unroll
            for (int k = 0; k < 64; k++) {
                float rsk = rl(rs, k);
                float y1k = rl(v1, k) * rsk;
                float y2k = rl(v2, k) * rsk;
                if (t == k) {
                    y1s[t] = y1k; y2s[t] = y2k;
                    r1[(size_t)b * NA + TB + pb + t] = y1k;
                    r2[(size_t)b * NA + TB + pb + t] = y2k;
                }
                float lv = (t > k) ? T[(pb + t) * TSTR + pb + k] : 0.f;
                v1 -= lv * y1k;
                v2 -= lv * y2k;
            }
        }
        __syncthreads();

        if (msub > 0) {
            if (tid < msub) {
                const int row_l = pb + 64 + tid;
                float rv[64];
#pragma unroll
                for (int k = 0; k < 64; k++) rv[k] = T[row_l * TSTR + pb + k];
#pragma unroll
                for (int k = 0; k < 64; k++) {
                    float yk = rv[k] * invd[k];
                    rv[k] = yk;
                    const float* LTrow = &T[(pb + k) * TSTR + pb];
#pragma unroll
                    for (int i = k + 1; i < 64; i++)
                        rv[i] -= LTrow[i] * yk;
                }
#pragma unroll
                for (int k = 0; k < 64; k++) T[row_l * TSTR + pb + k] = rv[k];
                float a1 = 0.f, a2 = 0.f;
#pragma unroll
                for (int k = 0; k < 64; k++) {
                    a1 = fmaf(rv[k], y1s[k], a1);
                    a2 = fmaf(rv[k], y2s[k], a2);
                }
                r1[(size_t)b * NA + TB + row_l] -= a1;
                r2[(size_t)b * NA + TB + row_l] -= a2;
            }
            __syncthreads();

            const int rbase = pb + 64;
            if (p == 0) {
                // 128x128 trailing, 512 threads: 4x8 per thread (rg 0..31, cg 0..15)
                const int rg = tid >> 4, cg = tid & 15;
                float acc[4][8];
#pragma unroll
                for (int rr = 0; rr < 4; rr++)
#pragma unroll
                    for (int cc = 0; cc < 8; cc++)
                        acc[rr][cc] = T[(rbase + rg * 4 + rr) * TSTR + rbase + cg * 8 + cc];
#pragma unroll 4
                for (int k = 0; k < 64; k++) {
                    float ai[4], bj[8];
#pragma unroll
                    for (int rr = 0; rr < 4; rr++)
                        ai[rr] = T[(rbase + rg * 4 + rr) * TSTR + pb + k];
#pragma unroll
                    for (int cc = 0; cc < 8; cc++)
                        bj[cc] = T[(rbase + cg * 8 + cc) * TSTR + pb + k];
#pragma unroll
                    for (int rr = 0; rr < 4; rr++)
#pragma unroll
                        for (int cc = 0; cc < 8; cc++)
                            acc[rr][cc] = fmaf(-ai[rr], bj[cc], acc[rr][cc]);
                }
#pragma unroll
                for (int rr = 0; rr < 4; rr++)
#pragma unroll
                    for (int cc = 0; cc < 8; cc++)
                        T[(rbase + rg * 4 + rr) * TSTR + rbase + cg * 8 + cc] = acc[rr][cc];
            } else {
                // 64x64 trailing, 512 threads: 2x4 per thread (rg 0..31, cg 0..15)
                const int rg = tid >> 4, cg = tid & 15;
                float acc[2][4];
#pragma unroll
                for (int rr = 0; rr < 2; rr++)
#pragma unroll
                    for (int cc = 0; cc < 4; cc++)
                        acc[rr][cc] = T[(rbase + rg * 2 + rr) * TSTR + rbase + cg * 4 + cc];
#pragma unroll 4
                for (int k = 0; k < 64; k++) {
                    float ai[2], bj[4];
#pragma unroll
                    for (int rr = 0; rr < 2; rr++)
                        ai[rr] = T[(rbase + rg * 2 + rr) * TSTR + pb + k];
#pragma unroll
                    for (int cc = 0; cc < 4; cc++)
                        bj[cc] = T[(rbase + cg * 4 + cc) * TSTR + pb + k];
#pragma unroll
                    for (int rr = 0; rr < 2; rr++)
#pragma unroll
                        for (int cc = 0; cc < 4; cc++)
                            acc[rr][cc] = fmaf(-ai[rr], bj[cc], acc[rr][cc]);
                }
#pragma unroll
                for (int rr = 0; rr < 2; rr++)
#pragma unroll
                    for (int cc = 0; cc < 4; cc++)
                        T[(rbase + rg * 2 + rr) * TSTR + rbase + cg * 4 + cc] = acc[rr][cc];
            }
        }
        __syncthreads();
    }

    for (int f = tid; f < TS * TS; f += 512) {
        int row = f / TS, c = f - row * TS;
        Cb[(size_t)(TB + row) * NA + TB + c] = T[row * TSTR + c];
    }
}

// ------------------------------------------- K4: backward-only solve (grid = B x 2)
__global__ void __launch_bounds__(512, 1) k_back(const float* __restrict__ C,
                                                 float* __restrict__ r1g,
                                                 float* __restrict__ r2g) {
    const int b = blockIdx.x;
    const int rhs = blockIdx.y;
    const float* Cb = C + (size_t)b * NN;
    const int tid = threadIdx.x;
    __shared__ float D[64 * 65];
    __shared__ float r[NA];
    __shared__ float pb[4][NA];

    float* rg = rhs ? r2g : r1g;
    r[tid] = rg[(size_t)b * NA + tid];

    const int ii = tid & 127;
    const int gg = tid >> 7;
    for (int j = 7; j >= 0; j--) {
        const int jb = j * 64;
        __syncthreads();
#pragma unroll
        for (int e = 0; e < 8; e++) {
            int f = e * 512 + tid;
            int row = f >> 6, cc = f & 63;
            D[row * 65 + cc] = Cb[(size_t)(jb + row) * NA + jb + cc];
        }
        __syncthreads();
        if (tid < 64) {
            float val = r[jb + tid];
            float idg = 1.0f / D[tid * 65 + tid];
#pragma unroll
            for (int k = 63; k >= 0; k--) {
                float xk = rl(val, k) * rl(idg, k);
                if (tid == k) r[jb + k] = xk;
                float lv = (tid < k) ? D[k * 65 + tid] : 0.f;
                val -= lv * xk;
            }
        }
        __syncthreads();
        if (jb > 0) {
            const int nf4 = jb >> 2;
            float4 s1 = make_float4(0.f, 0.f, 0.f, 0.f);
            if (ii < nf4) {
#pragma unroll
                for (int gq = 0; gq < 16; gq++) {
                    int g = jb + gg * 16 + gq;
                    float x1 = r[g];
                    float4 Lv = *(const float4*)(Cb + (size_t)g * NA + ii * 4);
                    s1.x += Lv.x * x1; s1.y += Lv.y * x1; s1.z += Lv.z * x1; s1.w += Lv.w * x1;
                }
            }
            *(float4*)(&pb[gg][ii * 4]) = s1;
            __syncthreads();
            if (tid < jb)
                r[tid] -= pb[0][tid] + pb[1][tid] + pb[2][tid] + pb[3][tid];
        }
    }
    __syncthreads();

    rg[(size_t)b * NA + tid] = r[tid];
}

// ------------------------------------------- K5: mu, q, energy from x1, x2
__global__ void __launch_bounds__(512, 1) k_final(const float* __restrict__ x1,
                                                  const float* __restrict__ x2,
                                                  const float* __restrict__ chiA,
                                                  const float* __restrict__ Qtot,
                                                  float* __restrict__ out, int B) {
    const int b = blockIdx.x;
    const int tid = threadIdx.x;
    __shared__ float red[16];
    __shared__ float muS;

    float v1 = x1[(size_t)b * NA + tid];
    float v2 = x2[(size_t)b * NA + tid];

    float s1p = v1, s2p = v2;
#pragma unroll
    for (int off = 1; off < 64; off <<= 1) {
        s1p += __shfl_xor(s1p, off);
        s2p += __shfl_xor(s2p, off);
    }
    if ((tid & 63) == 0) { red[tid >> 6] = s1p; red[8 + (tid >> 6)] = s2p; }
    __syncthreads();
    if (tid == 0) {
        float s1 = 0.f, s2 = 0.f;
#pragma unroll
        for (int wv = 0; wv < 8; wv++) { s1 += red[wv]; s2 += red[8 + wv]; }
        muS = -(Qtot[b] + s1) / s2;
    }
    __syncthreads();
    float mu = muS;
    float qv = -v1 - mu * v2;
    out[B + (size_t)b * NA + tid] = qv;

    float eacc = chiA[b * NA + tid] * qv;
#pragma unroll
    for (int off = 1; off < 64; off <<= 1) eacc += __shfl_xor(eacc, off);
    __syncthreads();
    if ((tid & 63) == 0) red[tid >> 6] = eacc;
    __syncthreads();
    if (tid == 0) {
        float e = 0.f;
#pragma unroll
        for (int wv = 0; wv < 8; wv++) e += red[wv];
        out[b] = 0.5f * e - 0.5f * mu * Qtot[b];
    }
}

// ---------------------------------------------------------------- host launch
extern "C" void kernel_launch(void* const* d_in, const int* in_sizes, int n_in,
                              void* d_out, int out_size, void* d_ws, size_t ws_size,
                              hipStream_t stream) {
    const int B = in_sizes[3];          // 128 molecules
    const int N = in_sizes[2];          // 65536 atoms
    const float* feats = (const float*)d_in[0];
    const float* pos   = (const float*)d_in[1];
    const int*   type  = (const int*)d_in[2];
    const float* Qt    = (const float*)d_in[3];
    const float* w     = (const float*)d_in[4];
    const float* hard  = (const float*)d_in[5];
    const float* sig   = (const float*)d_in[6];
    float* out = (float*)d_out;
    float* ws  = (float*)d_ws;

    float* C    = ws;                       // B * 512 * 512
    float* chi  = ws + (size_t)B * NN;      // N
    float* diag = chi + N;                  // N
    float* sigA = diag + N;                 // N
    float* r1   = sigA + N;                 // N (rhs1: chi -> y -> x1)
    float* r2   = r1 + N;                   // N (rhs2: 1   -> y -> x2)

    k_pre<<<(N + 255) / 256, 256, 0, stream>>>(feats, w, type, hard, sig,
                                               chi, diag, sigA, r1, r2, N);

    static const int tilesJ[5] = {10, 6, 6, 3, 3};
    for (int j = 0; j < 5; j++) {
        k_panel<<<dim3(2, B), 256, 0, stream>>>(pos, sigA, diag, C, r1, r2, j);
        if (j == 0)
            k_trail<true><<<dim3(tilesJ[j], B), 256, 0, stream>>>(C, pos, sigA, diag, j);
        else
            k_trail<false><<<dim3(tilesJ[j], B), 256, 0, stream>>>(C, pos, sigA, diag, j);
    }
    k_tail<<<B, 512, 0, stream>>>(C, r1, r2);
    k_back<<<dim3(B, 2), 512, 0, stream>>>(C, r1, r2);
    k_final<<<B, 512, 0, stream>>>(r1, r2, chi, Qt, out, B);
}

// Round 15
// 692.526 us; speedup vs baseline: 1.1639x; 1.0388x over previous
//
#include <hip/hip_runtime.h>
#include <math.h>

#define NA 512
#define NN (NA*NA)
#define COULOMB 14.399645478425668f
#define SQRT_PI 1.7724538509055160273f

// tail-fusion region: last 192 rows/cols handled by k_tail in LDS
#define TB 320
#define TS 192
#define TSTR 193

// f16 LDS row stride for MFMA panel tiles (72*2=144B, multiple of 16B)
#define FST 72

typedef float v2f __attribute__((ext_vector_type(2)));
typedef _Float16 half8 __attribute__((ext_vector_type(8)));
typedef float floatx16 __attribute__((ext_vector_type(16)));

__device__ __forceinline__ float rl(float x, int lane) {
    return __int_as_float(__builtin_amdgcn_readlane(__float_as_int(x), lane));
}

__device__ __forceinline__ float pair_val(float dx, float dy, float dz,
                                          float s2i, float s2k) {
    float d2 = dx*dx + dy*dy + dz*dz;
    float rinv = rsqrtf(d2);
    return COULOMB * erff(d2 * rinv * rsqrtf(2.f * (s2i + s2k))) * rinv;
}

// ---------------------------------------------------------------- K1: per-atom
// Also initializes the two RHS vectors: r1 = chi, r2 = 1.
__global__ void k_pre(const float* __restrict__ feats, const float* __restrict__ w,
                      const int* __restrict__ type, const float* __restrict__ hard,
                      const float* __restrict__ sigma,
                      float* __restrict__ chi, float* __restrict__ diag,
                      float* __restrict__ sigA,
                      float* __restrict__ r1, float* __restrict__ r2, int N) {
    __shared__ float wl[64];
    int tid = threadIdx.x;
    if (tid < 64) wl[tid] = w[tid];
    __syncthreads();
    int i = blockIdx.x * 256 + tid;
    if (i >= N) return;
    const float4* fp = (const float4*)(feats + (size_t)i * 64);
    float acc = 0.f;
#pragma unroll
    for (int q = 0; q < 16; q++) {
        float4 v = fp[q];
        acc += v.x * wl[4*q] + v.y * wl[4*q+1] + v.z * wl[4*q+2] + v.w * wl[4*q+3];
    }
    chi[i] = acc;
    r1[i] = acc;
    r2[i] = 1.0f;
    int t = type[i];
    float s = sigma[t];
    float h = hard[t];
    sigA[i] = s;
    diag[i] = h * h + COULOMB / (SQRT_PI * s);
}

// ------------------------------------------- K2: diag factor + split panel trsm (j<=4)
// Forward substitution for BOTH RHS fused here (round-11 proven).
__global__ void __launch_bounds__(256, 1) k_panel(const float* __restrict__ pos,
                                                  const float* __restrict__ sigA,
                                                  const float* __restrict__ diagA,
                                                  float* __restrict__ C,
                                                  float* __restrict__ r1,
                                                  float* __restrict__ r2, const int j) {
    const int q = blockIdx.x;
    const int b = blockIdx.y;
    float* __restrict__ Cb = C + (size_t)b * NN;
    const int jb = j * 64;
    const int m = NA - jb - 64;
    const int tid = threadIdx.x;
    __shared__ float D[64 * 65];
    __shared__ float DT[64 * 64];
    __shared__ float invd[64];
    __shared__ float y1s[64], y2s[64];
    __shared__ float px[NA], py[NA], pz[NA], s2s[NA];

    if (j == 0) {
#pragma unroll
        for (int e = 0; e < 2; e++) {
            int i = e * 256 + tid;
            px[i] = pos[((size_t)b * NA + i) * 3 + 0];
            py[i] = pos[((size_t)b * NA + i) * 3 + 1];
            pz[i] = pos[((size_t)b * NA + i) * 3 + 2];
            float s = sigA[b * NA + i];
            s2s[i] = s * s;
        }
        __syncthreads();
    }

#pragma unroll
    for (int e = 0; e < 16; e++) {
        int f = e * 256 + tid;
        int rr = f >> 6, cc = f & 63;
        float v;
        if (j == 0) {
            if (rr == cc) v = diagA[b * NA + rr];
            else v = pair_val(px[rr]-px[cc], py[rr]-py[cc], pz[rr]-pz[cc], s2s[rr], s2s[cc]);
        } else {
            v = Cb[(size_t)(jb + rr) * NA + jb + cc];
        }
        D[rr * 65 + cc] = v;
    }

    const int h = m >> 1;
    const int r0 = q ? h : 0;
    const int nr = q ? (m - h) : h;
    const int r = tid - 32;
    const bool hasrow = (r >= 0 && r < nr);
    const int grow = jb + 64 + r0 + r;
    float rv[64];
    if (hasrow) {
        if (j == 0) {
#pragma unroll
            for (int k = 0; k < 64; k++)
                rv[k] = pair_val(px[grow]-px[k], py[grow]-py[k], pz[grow]-pz[k],
                                 s2s[grow], s2s[k]);
        } else {
            const float4* rp = (const float4*)(Cb + (size_t)grow * NA + jb);
#pragma unroll
            for (int qq = 0; qq < 16; qq++) {
                float4 v = rp[qq];
                rv[4*qq] = v.x; rv[4*qq+1] = v.y; rv[4*qq+2] = v.z; rv[4*qq+3] = v.w;
            }
        }
    }
    __syncthreads();

    if (tid < 64) {
        const int t = tid;
        float cl[64];
#pragma unroll
        for (int i = 0; i < 64; i++) cl[i] = (i >= t) ? D[i * 65 + t] : D[t * 65 + i];
#pragma unroll
        for (int k = 0; k < 64; k++) {
            float pivot = rl(cl[k], k);
            float invp = 1.0f / pivot;
            float factor = (t > k) ? (cl[k] * invp) : 0.0f;
#pragma unroll
            for (int i = k + 1; i < 64; i++) {
                float bc = rl(cl[i], k);
                cl[i] -= bc * factor;
            }
        }
        float rs = 1.0f / sqrtf(cl[t]);
        invd[t] = rs;
#pragma unroll
        for (int i = 0; i < 64; i++)
            if (i >= t) D[i * 65 + t] = cl[i] * rs;

        // ---- fused forward substitution: solve L_jj y = r_j for both RHS.
        float v1 = r1[(size_t)b * NA + jb + t];
        float v2 = r2[(size_t)b * NA + jb + t];
#pragma unroll
        for (int k = 0; k < 64; k++) {
            float rsk = rl(rs, k);
            float y1k = rl(v1, k) * rsk;
            float y2k = rl(v2, k) * rsk;
            if (t == k) {
                y1s[t] = y1k; y2s[t] = y2k;
                if (q == 0) {
                    r1[(size_t)b * NA + jb + t] = y1k;
                    r2[(size_t)b * NA + jb + t] = y2k;
                }
            }
            float lv = (t > k) ? D[t * 65 + k] : 0.f;
            v1 -= lv * y1k;
            v2 -= lv * y2k;
        }
    }
    __syncthreads();

#pragma unroll
    for (int e = 0; e < 16; e++) {
        int f = e * 256 + tid;
        int row = f >> 6, cc = f & 63;
        float v = D[row * 65 + cc];
        DT[row * 64 + cc] = (cc < row) ? v : 0.f;
        if (q == 0 && cc <= row) Cb[(size_t)(jb + row) * NA + jb + cc] = v;
    }
    __syncthreads();

    if (hasrow) {
#pragma unroll
        for (int k = 0; k < 64; k++) {
            float acc = rv[k];
            const float4* Lr = (const float4*)(DT + k * 64);
            const int k4 = k >> 2;
#pragma unroll
            for (int t4 = 0; t4 < k4; t4++) {
                float4 Lv = Lr[t4];
                acc -= Lv.x * rv[4*t4] + Lv.y * rv[4*t4+1] + Lv.z * rv[4*t4+2] + Lv.w * rv[4*t4+3];
            }
#pragma unroll
            for (int tt = k4 * 4; tt < k; tt++) acc -= DT[k * 64 + tt] * rv[tt];
            rv[k] = acc * invd[k];
        }
        float4* rp = (float4*)(Cb + (size_t)grow * NA + jb);
#pragma unroll
        for (int qq = 0; qq < 16; qq++)
            rp[qq] = make_float4(rv[4*qq], rv[4*qq+1], rv[4*qq+2], rv[4*qq+3]);

        // ---- fused forward update: r[grow] -= L_row . y_j (both RHS).
        float a1 = 0.f, a2 = 0.f;
#pragma unroll
        for (int k = 0; k < 64; k++) {
            a1 = fmaf(rv[k], y1s[k], a1);
            a2 = fmaf(rv[k], y2s[k], a2);
        }
        r1[(size_t)b * NA + grow] -= a1;
        r2[(size_t)b * NA + grow] -= a2;
    }
}

// ------------------------------------------- K3: trailing update j=0 (GEN) — proven scalar
__global__ void __launch_bounds__(256, 2) k_trail0(float* __restrict__ C,
                                                   const float* __restrict__ pos,
                                                   const float* __restrict__ sigA,
                                                   const float* __restrict__ diagA) {
    const int b = blockIdx.y;
    float* __restrict__ Cb = C + (size_t)b * NN;
    const int jb = 0;
    const int m = NA - 64;
    int t = blockIdx.x;
    int RI = 0;
    while (t >= RI + 1) { t -= RI + 1; RI++; }
    const int RJ = t;
    const int RB = RI * 128, CB = RJ * 128;
    const int vr = min(128, m - RB);
    const int vc = min(128, m - CB);
    const int tid = threadIdx.x;
    const int rg = tid >> 4, cg = tid & 15;

    __shared__ float As[128 * 66];
    __shared__ float Bs[128 * 66];

    v2f ac2[8][8];

    {
        __shared__ float pAx[128], pAy[128], pAz[128], sA[128], dA[128];
        __shared__ float pBx[128], pBy[128], pBz[128], sB[128];
        if (tid < 128) {
            if (RB + tid < m) {
                int ga = b * NA + jb + 64 + RB + tid;
                pAx[tid] = pos[(size_t)ga * 3 + 0];
                pAy[tid] = pos[(size_t)ga * 3 + 1];
                pAz[tid] = pos[(size_t)ga * 3 + 2];
                float s = sigA[ga]; sA[tid] = s * s;
                dA[tid] = diagA[ga];
            }
        } else {
            int u = tid - 128;
            if (CB + u < m) {
                int gb = b * NA + jb + 64 + CB + u;
                pBx[u] = pos[(size_t)gb * 3 + 0];
                pBy[u] = pos[(size_t)gb * 3 + 1];
                pBz[u] = pos[(size_t)gb * 3 + 2];
                float s = sigA[gb]; sB[u] = s * s;
            }
        }
        __syncthreads();
#pragma unroll
        for (int rr = 0; rr < 8; rr++) {
            int row = rg * 8 + rr;
#pragma unroll
            for (int cc = 0; cc < 8; cc++) {
                int col = cg + 16 * cc;
                float iv;
                if (RB + row == CB + col)
                    iv = dA[row];
                else
                    iv = pair_val(pAx[row]-pBx[col], pAy[row]-pBy[col],
                                  pAz[row]-pBz[col], sA[row], sB[col]);
                ac2[rr][cc].x = iv;
                ac2[rr][cc].y = 0.f;
            }
        }
        __syncthreads();
    }

    const float* Pan = Cb + (size_t)(jb + 64) * NA + jb;
#pragma unroll
    for (int e = 0; e < 8; e++) {
        int f = e * 256 + tid;
        int row = f >> 4, s = f & 15;
        float4 v = make_float4(0.f, 0.f, 0.f, 0.f);
        if (row < vr) v = *(const float4*)(Pan + (size_t)(RB + row) * NA + s * 4);
        As[row * 66 + s * 4 + 0] = v.x;
        As[row * 66 + s * 4 + 1] = v.y;
        As[row * 66 + s * 4 + 2] = v.z;
        As[row * 66 + s * 4 + 3] = v.w;
        float4 u = make_float4(0.f, 0.f, 0.f, 0.f);
        if (row < vc) u = *(const float4*)(Pan + (size_t)(CB + row) * NA + s * 4);
        Bs[row * 66 + s * 4 + 0] = u.x;
        Bs[row * 66 + s * 4 + 1] = u.y;
        Bs[row * 66 + s * 4 + 2] = u.z;
        Bs[row * 66 + s * 4 + 3] = u.w;
    }
    __syncthreads();

#pragma unroll 2
    for (int k = 0; k < 64; k += 2) {
        v2f ai2[8], bj2[8];
#pragma unroll
        for (int rr = 0; rr < 8; rr++)
            ai2[rr] = *(const v2f*)&As[(rg * 8 + rr) * 66 + k];
#pragma unroll
        for (int cc = 0; cc < 8; cc++)
            bj2[cc] = *(const v2f*)&Bs[(cg + 16 * cc) * 66 + k];
#pragma unroll
        for (int rr = 0; rr < 8; rr++)
#pragma unroll
            for (int cc = 0; cc < 8; cc++) {
                ac2[rr][cc].x = fmaf(-ai2[rr].x, bj2[cc].x, ac2[rr][cc].x);
                ac2[rr][cc].y = fmaf(-ai2[rr].y, bj2[cc].y, ac2[rr][cc].y);
            }
    }

    const int GRB = jb + 64 + RB, GCB = jb + 64 + CB;
#pragma unroll
    for (int rr = 0; rr < 8; rr++) {
        int row = rg * 8 + rr;
        if (row < vr) {
#pragma unroll
            for (int cc = 0; cc < 8; cc++) {
                int col = cg + 16 * cc;
                if (col < vc)
                    Cb[(size_t)(GRB + row) * NA + GCB + col] = ac2[rr][cc].x + ac2[rr][cc].y;
            }
        }
    }
}

// ------------------------------------------- K3m: trailing update j>=1 — MFMA fp16x2 SYRK
// acc init = plain guarded C loads at the m74/m101-VERIFIED C/D coords
// (col=lane&31, row=(reg&3)+8*(reg>>2)+4*(lane>>5)). Panel staged as fp16 split
// p=ph+pl (A-side negated); products via 3 MFMA (hh,hl,lh) — error ~2^-22|pq|.
// A/B frag k-mapping: any lane-consistent bijection cancels (same map for A and B).
// LDS arrays explicitly 16B-aligned for ds_read_b128.
__global__ void __launch_bounds__(256, 2) k_trailm(float* __restrict__ C, const int j) {
    const int b = blockIdx.y;
    float* __restrict__ Cb = C + (size_t)b * NN;
    const int jb = j * 64;
    const int m = NA - jb - 64;
    int t = blockIdx.x;
    int RI = 0;
    while (t >= RI + 1) { t -= RI + 1; RI++; }
    const int RJ = t;
    const int RB = RI * 128, CB = RJ * 128;
    const int vr = min(128, m - RB);
    const int vc = min(128, m - CB);
    const int tid = threadIdx.x;
    const int lane = tid & 63;
    const int wv = tid >> 6;
    const int tr0 = (wv >> 1) * 2;
    const int tc0 = (wv & 1) * 2;
    const int lcol = lane & 31;
    const int lrhi = (lane >> 5) * 4;
    const int kfo = (lane >> 5) * 8;

    __shared__ __attribute__((aligned(16))) _Float16 Ash[128 * FST];
    __shared__ __attribute__((aligned(16))) _Float16 Asl[128 * FST];
    __shared__ __attribute__((aligned(16))) _Float16 Bsh[128 * FST];
    __shared__ __attribute__((aligned(16))) _Float16 Bsl[128 * FST];

    floatx16 acc[2][2];

    const int GRB = jb + 64 + RB, GCB = jb + 64 + CB;
#pragma unroll
    for (int a = 0; a < 2; a++)
#pragma unroll
        for (int bb = 0; bb < 2; bb++)
#pragma unroll
            for (int r = 0; r < 16; r++) {
                int row = (tr0 + a) * 32 + (r & 3) + 8 * (r >> 2) + lrhi;
                int col = (tc0 + bb) * 32 + lcol;
                acc[a][bb][r] = (row < vr && col < vc)
                    ? Cb[(size_t)(GRB + row) * NA + GCB + col] : 0.f;
            }

    // ---- stage panel rows as fp16x2 split (A-side negated)
    const float* Pan = Cb + (size_t)(jb + 64) * NA + jb;
#pragma unroll
    for (int e = 0; e < 8; e++) {
        int f = e * 256 + tid;
        int row = f >> 4, s = f & 15;
        float4 v = make_float4(0.f, 0.f, 0.f, 0.f);
        if (row < vr) v = *(const float4*)(Pan + (size_t)(RB + row) * NA + s * 4);
        float av[4] = {v.x, v.y, v.z, v.w};
#pragma unroll
        for (int c = 0; c < 4; c++) {
            float nx = -av[c];
            _Float16 hh = (_Float16)nx;
            _Float16 ll = (_Float16)(nx - (float)hh);
            Ash[row * FST + s * 4 + c] = hh;
            Asl[row * FST + s * 4 + c] = ll;
        }
        float4 u = make_float4(0.f, 0.f, 0.f, 0.f);
        if (row < vc) u = *(const float4*)(Pan + (size_t)(CB + row) * NA + s * 4);
        float bv[4] = {u.x, u.y, u.z, u.w};
#pragma unroll
        for (int c = 0; c < 4; c++) {
            float x = bv[c];
            _Float16 hh = (_Float16)x;
            _Float16 ll = (_Float16)(x - (float)hh);
            Bsh[row * FST + s * 4 + c] = hh;
            Bsl[row * FST + s * 4 + c] = ll;
        }
    }
    __syncthreads();

    // ---- MFMA k-loop: K = 64 = 4 steps of 16
#pragma unroll
    for (int ks = 0; ks < 4; ks++) {
        half8 Ah[2], Al[2], Bh[2], Bl[2];
#pragma unroll
        for (int a = 0; a < 2; a++) {
            int off = ((tr0 + a) * 32 + lcol) * FST + ks * 16 + kfo;
            Ah[a] = *(const half8*)&Ash[off];
            Al[a] = *(const half8*)&Asl[off];
        }
#pragma unroll
        for (int bb = 0; bb < 2; bb++) {
            int off = ((tc0 + bb) * 32 + lcol) * FST + ks * 16 + kfo;
            Bh[bb] = *(const half8*)&Bsh[off];
            Bl[bb] = *(const half8*)&Bsl[off];
        }
#pragma unroll
        for (int a = 0; a < 2; a++)
#pragma unroll
            for (int bb = 0; bb < 2; bb++) {
                acc[a][bb] = __builtin_amdgcn_mfma_f32_32x32x16_f16(Ah[a], Bh[bb], acc[a][bb], 0, 0, 0);
                acc[a][bb] = __builtin_amdgcn_mfma_f32_32x32x16_f16(Ah[a], Bl[bb], acc[a][bb], 0, 0, 0);
                acc[a][bb] = __builtin_amdgcn_mfma_f32_32x32x16_f16(Al[a], Bh[bb], acc[a][bb], 0, 0, 0);
            }
    }

#pragma unroll
    for (int a = 0; a < 2; a++)
#pragma unroll
        for (int bb = 0; bb < 2; bb++)
#pragma unroll
            for (int r = 0; r < 16; r++) {
                int row = (tr0 + a) * 32 + (r & 3) + 8 * (r >> 2) + lrhi;
                int col = (tc0 + bb) * 32 + lcol;
                if (row < vr && col < vc)
                    Cb[(size_t)(GRB + row) * NA + GCB + col] = acc[a][bb][r];
            }
}

// ------------------------------------------- K3b: fused tail (j=5,6,7) — round-13 proven
__global__ void __launch_bounds__(512, 1) k_tail(float* __restrict__ C,
                                                 float* __restrict__ r1,
                                                 float* __restrict__ r2) {
    const int b = blockIdx.x;
    float* __restrict__ Cb = C + (size_t)b * NN;
    const int tid = threadIdx.x;
    __shared__ float T[TS * TSTR];
    __shared__ float invd[64], y1s[64], y2s[64];

    for (int f = tid; f < TS * TS; f += 512) {
        int row = f / TS, c = f - row * TS;
        T[row * TSTR + c] = Cb[(size_t)(TB + row) * NA + TB + c];
    }
    __syncthreads();

#pragma unroll 1
    for (int p = 0; p < 3; p++) {
        const int pb = p * 64;
        const int msub = TS - pb - 64;

        if (tid < 64) {
            const int t = tid;
            float cl[64];
#pragma unroll
            for (int i = 0; i < 64; i++)
                cl[i] = (i >= t) ? T[(pb + i) * TSTR + pb + t]
                                 : T[(pb + t) * TSTR + pb + i];
#pragma unroll
            for (int k = 0; k < 64; k++) {
                float pivot = rl(cl[k], k);
                float invp = 1.0f / pivot;
                float factor = (t > k) ? (cl[k] * invp) : 0.0f;
#pragma unroll
                for (int i = k + 1; i < 64; i++) {
                    float bc = rl(cl[i], k);
                    cl[i] -= bc * factor;
                }
            }
            float rs = 1.0f / sqrtf(cl[t]);
            invd[t] = rs;
#pragma unroll
            for (int i = 0; i < 64; i++) {
                float lv = cl[i] * rs;
                if (i >= t) T[(pb + i) * TSTR + pb + t] = lv;   // L (column t)
                if (i > t)  T[(pb + t) * TSTR + pb + i] = lv;   // L^T (row t)
            }
            // fused forward substitution, both RHS
            float v1 = r1[(size_t)b * NA + TB + pb + t];
            float v2 = r2[(size_t)b * NA + TB + pb + t];
#pragma unroll
            for (int k = 0; k < 64; k++) {
                float rsk = rl(rs, k);
                float y1k = rl(v1, k) * rsk;
                float y2k = rl(v2, k) * rsk;
                if (t == k) {
                    y1s[t] = y1k; y2s[t] = y2k;
                    r1[(size_t)b * NA + TB + pb + t] = y1k;
                    r2[(size_t)b * NA + TB + pb + t] = y2k;
                }
                float lv = (t > k) ? T[(pb + t) * TSTR + pb + k] : 0.f;
                v1 -= lv * y1k;
                v2 -= lv * y2k;
            }
        }
        __syncthreads();

        if (msub > 0) {
            if (tid < msub) {
                const int row_l = pb + 64 + tid;
                float rv[64];
#pragma unroll
                for (int k = 0; k < 64; k++) rv[k] = T[row_l * TSTR + pb + k];
#pragma unroll
                for (int k = 0; k < 64; k++) {
                    float yk = rv[k] * invd[k];
                    rv[k] = yk;
                    const float* LTrow = &T[(pb + k) * TSTR + pb];
#pragma unroll
                    for (int i = k + 1; i < 64; i++)
                        rv[i] -= LTrow[i] * yk;
                }
#pragma unroll
                for (int k = 0; k < 64; k++) T[row_l * TSTR + pb + k] = rv[k];
                float a1 = 0.f, a2 = 0.f;
#pragma unroll
                for (int k = 0; k < 64; k++) {
                    a1 = fmaf(rv[k], y1s[k], a1);
                    a2 = fmaf(rv[k], y2s[k], a2);
                }
                r1[(size_t)b * NA + TB + row_l] -= a1;
                r2[(size_t)b * NA + TB + row_l] -= a2;
            }
            __syncthreads();

            const int rbase = pb + 64;
            if (p == 0) {
                const int rg = tid >> 4, cg = tid & 15;
                float acc[4][8];
#pragma unroll
                for (int rr = 0; rr < 4; rr++)
#pragma unroll
                    for (int cc = 0; cc < 8; cc++)
                        acc[rr][cc] = T[(rbase + rg * 4 + rr) * TSTR + rbase + cg * 8 + cc];
#pragma unroll 4
                for (int k = 0; k < 64; k++) {
                    float ai[4], bj[8];
#pragma unroll
                    for (int rr = 0; rr < 4; rr++)
                        ai[rr] = T[(rbase + rg * 4 + rr) * TSTR + pb + k];
#pragma unroll
                    for (int cc = 0; cc < 8; cc++)
                        bj[cc] = T[(rbase + cg * 8 + cc) * TSTR + pb + k];
#pragma unroll
                    for (int rr = 0; rr < 4; rr++)
#pragma unroll
                        for (int cc = 0; cc < 8; cc++)
                            acc[rr][cc] = fmaf(-ai[rr], bj[cc], acc[rr][cc]);
                }
#pragma unroll
                for (int rr = 0; rr < 4; rr++)
#pragma unroll
                    for (int cc = 0; cc < 8; cc++)
                        T[(rbase + rg * 4 + rr) * TSTR + rbase + cg * 8 + cc] = acc[rr][cc];
            } else {
                const int rg = tid >> 4, cg = tid & 15;
                float acc[2][4];
#pragma unroll
                for (int rr = 0; rr < 2; rr++)
#pragma unroll
                    for (int cc = 0; cc < 4; cc++)
                        acc[rr][cc] = T[(rbase + rg * 2 + rr) * TSTR + rbase + cg * 4 + cc];
#pragma unroll 4
                for (int k = 0; k < 64; k++) {
                    float ai[2], bj[4];
#pragma unroll
                    for (int rr = 0; rr < 2; rr++)
                        ai[rr] = T[(rbase + rg * 2 + rr) * TSTR + pb + k];
#pragma unroll
                    for (int cc = 0; cc < 4; cc++)
                        bj[cc] = T[(rbase + cg * 4 + cc) * TSTR + pb + k];
#pragma unroll
                    for (int rr = 0; rr < 2; rr++)
#pragma unroll
                        for (int cc = 0; cc < 4; cc++)
                            acc[rr][cc] = fmaf(-ai[rr], bj[cc], acc[rr][cc]);
                }
#pragma unroll
                for (int rr = 0; rr < 2; rr++)
#pragma unroll
                    for (int cc = 0; cc < 4; cc++)
                        T[(rbase + rg * 2 + rr) * TSTR + rbase + cg * 4 + cc] = acc[rr][cc];
            }
        }
        __syncthreads();
    }

    for (int f = tid; f < TS * TS; f += 512) {
        int row = f / TS, c = f - row * TS;
        Cb[(size_t)(TB + row) * NA + TB + c] = T[row * TSTR + c];
    }
}

// ------------------------------------------- K4: backward-only solve (grid = B x 2)
__global__ void __launch_bounds__(512, 1) k_back(const float* __restrict__ C,
                                                 float* __restrict__ r1g,
                                                 float* __restrict__ r2g) {
    const int b = blockIdx.x;
    const int rhs = blockIdx.y;
    const float* Cb = C + (size_t)b * NN;
    const int tid = threadIdx.x;
    __shared__ float D[64 * 65];
    __shared__ float r[NA];
    __shared__ float pb[4][NA];

    float* rg = rhs ? r2g : r1g;
    r[tid] = rg[(size_t)b * NA + tid];

    const int ii = tid & 127;
    const int gg = tid >> 7;
    for (int j = 7; j >= 0; j--) {
        const int jb = j * 64;
        __syncthreads();
#pragma unroll
        for (int e = 0; e < 8; e++) {
            int f = e * 512 + tid;
            int row = f >> 6, cc = f & 63;
            D[row * 65 + cc] = Cb[(size_t)(jb + row) * NA + jb + cc];
        }
        __syncthreads();
        if (tid < 64) {
            float val = r[jb + tid];
            float idg = 1.0f / D[tid * 65 + tid];
#pragma unroll
            for (int k = 63; k >= 0; k--) {
                float xk = rl(val, k) * rl(idg, k);
                if (tid == k) r[jb + k] = xk;
                float lv = (tid < k) ? D[k * 65 + tid] : 0.f;
                val -= lv * xk;
            }
        }
        __syncthreads();
        if (jb > 0) {
            const int nf4 = jb >> 2;
            float4 s1 = make_float4(0.f, 0.f, 0.f, 0.f);
            if (ii < nf4) {
#pragma unroll
                for (int gq = 0; gq < 16; gq++) {
                    int g = jb + gg * 16 + gq;
                    float x1 = r[g];
                    float4 Lv = *(const float4*)(Cb + (size_t)g * NA + ii * 4);
                    s1.x += Lv.x * x1; s1.y += Lv.y * x1; s1.z += Lv.z * x1; s1.w += Lv.w * x1;
                }
            }
            *(float4*)(&pb[gg][ii * 4]) = s1;
            __syncthreads();
            if (tid < jb)
                r[tid] -= pb[0][tid] + pb[1][tid] + pb[2][tid] + pb[3][tid];
        }
    }
    __syncthreads();

    rg[(size_t)b * NA + tid] = r[tid];
}

// ------------------------------------------- K5: mu, q, energy from x1, x2
__global__ void __launch_bounds__(512, 1) k_final(const float* __restrict__ x1,
                                                  const float* __restrict__ x2,
                                                  const float* __restrict__ chiA,
                                                  const float* __restrict__ Qtot,
                                                  float* __restrict__ out, int B) {
    const int b = blockIdx.x;
    const int tid = threadIdx.x;
    __shared__ float red[16];
    __shared__ float muS;

    float v1 = x1[(size_t)b * NA + tid];
    float v2 = x2[(size_t)b * NA + tid];

    float s1p = v1, s2p = v2;
#pragma unroll
    for (int off = 1; off < 64; off <<= 1) {
        s1p += __shfl_xor(s1p, off);
        s2p += __shfl_xor(s2p, off);
    }
    if ((tid & 63) == 0) { red[tid >> 6] = s1p; red[8 + (tid >> 6)] = s2p; }
    __syncthreads();
    if (tid == 0) {
        float s1 = 0.f, s2 = 0.f;
#pragma unroll
        for (int wv = 0; wv < 8; wv++) { s1 += red[wv]; s2 += red[8 + wv]; }
        muS = -(Qtot[b] + s1) / s2;
    }
    __syncthreads();
    float mu = muS;
    float qv = -v1 - mu * v2;
    out[B + (size_t)b * NA + tid] = qv;

    float eacc = chiA[b * NA + tid] * qv;
#pragma unroll
    for (int off = 1; off < 64; off <<= 1) eacc += __shfl_xor(eacc, off);
    __syncthreads();
    if ((tid & 63) == 0) red[tid >> 6] = eacc;
    __syncthreads();
    if (tid == 0) {
        float e = 0.f;
#pragma unroll
        for (int wv = 0; wv < 8; wv++) e += red[wv];
        out[b] = 0.5f * e - 0.5f * mu * Qtot[b];
    }
}

// ---------------------------------------------------------------- host launch
extern "C" void kernel_launch(void* const* d_in, const int* in_sizes, int n_in,
                              void* d_out, int out_size, void* d_ws, size_t ws_size,
                              hipStream_t stream) {
    const int B = in_sizes[3];          // 128 molecules
    const int N = in_sizes[2];          // 65536 atoms
    const float* feats = (const float*)d_in[0];
    const float* pos   = (const float*)d_in[1];
    const int*   type  = (const int*)d_in[2];
    const float* Qt    = (const float*)d_in[3];
    const float* w     = (const float*)d_in[4];
    const float* hard  = (const float*)d_in[5];
    const float* sig   = (const float*)d_in[6];
    float* out = (float*)d_out;
    float* ws  = (float*)d_ws;

    float* C    = ws;                       // B * 512 * 512
    float* chi  = ws + (size_t)B * NN;      // N
    float* diag = chi + N;                  // N
    float* sigA = diag + N;                 // N
    float* r1   = sigA + N;                 // N (rhs1: chi -> y -> x1)
    float* r2   = r1 + N;                   // N (rhs2: 1   -> y -> x2)

    k_pre<<<(N + 255) / 256, 256, 0, stream>>>(feats, w, type, hard, sig,
                                               chi, diag, sigA, r1, r2, N);

    static const int tilesJ[5] = {10, 6, 6, 3, 3};
    for (int j = 0; j < 5; j++) {
        k_panel<<<dim3(2, B), 256, 0, stream>>>(pos, sigA, diag, C, r1, r2, j);
        if (j == 0)
            k_trail0<<<dim3(tilesJ[j], B), 256, 0, stream>>>(C, pos, sigA, diag);
        else
            k_trailm<<<dim3(tilesJ[j], B), 256, 0, stream>>>(C, j);
    }
    k_tail<<<B, 512, 0, stream>>>(C, r1, r2);
    k_back<<<dim3(B, 2), 512, 0, stream>>>(C, r1, r2);
    k_final<<<B, 512, 0, stream>>>(r1, r2, chi, Qt, out, B);
}